// Round 2
// 383.238 us; speedup vs baseline: 1.2273x; 1.2273x over previous
//
#include <hip/hip_runtime.h>
#include <hip/hip_bf16.h>
#include <math.h>

#define DD 768
#define HH 3072
#define EE 8
#define NN 2048   // B*T tokens
#define PP 5120   // max padded compact rows (4096 + 8*128)
#define PT 40     // max padded m-tiles (PP/128)

typedef __attribute__((ext_vector_type(8))) short short8;   // 8 bf16 MFMA operand
typedef __attribute__((ext_vector_type(4))) float floatx4;  // MFMA accumulator

typedef const __attribute__((address_space(1))) void gas_void;
typedef __attribute__((address_space(3))) void las_void;

__device__ __forceinline__ void gld16(const void* g, void* l) {
    // async global->LDS DMA, 16B/lane; LDS dest = wave-uniform base + lane*16
    __builtin_amdgcn_global_load_lds((gas_void*)g, (las_void*)l, 16, 0, 0);
}

__device__ __forceinline__ unsigned short f2bf(float f) {
    union { float f; unsigned int u; } v; v.f = f;
    unsigned int u = v.u;
    u += 0x7fffu + ((u >> 16) & 1u);   // RNE (inputs finite)
    return (unsigned short)(u >> 16);
}

// ---------------------------------------------------------------------------
// 1. Routing: z3 = x.Wr^T ; logits = z3.dirs^T ; softmax ; top-2 ; gates
// ---------------------------------------------------------------------------
__global__ __launch_bounds__(256) void routing_kernel(
    const float* __restrict__ x, const float* __restrict__ Wr,
    int* __restrict__ counts, float* __restrict__ psum,
    int* __restrict__ top_e, float* __restrict__ top_g)
{
    __shared__ float wr[3 * DD];
    __shared__ float lpsum[EE];
    int tid = threadIdx.x;
    for (int i = tid; i < 3 * DD; i += 256) wr[i] = Wr[i];
    if (tid < EE) lpsum[tid] = 0.f;
    __syncthreads();

    int n = blockIdx.x * 256 + tid;
    const float4* xp = (const float4*)(x + (size_t)n * DD);
    float z0 = 0.f, z1 = 0.f, z2 = 0.f;
#pragma unroll 8
    for (int i = 0; i < DD / 4; i++) {
        float4 v = xp[i];
        int d = i * 4;
        z0 = fmaf(v.x, wr[d], z0);         z0 = fmaf(v.y, wr[d+1], z0);
        z0 = fmaf(v.z, wr[d+2], z0);       z0 = fmaf(v.w, wr[d+3], z0);
        z1 = fmaf(v.x, wr[DD+d], z1);      z1 = fmaf(v.y, wr[DD+d+1], z1);
        z1 = fmaf(v.z, wr[DD+d+2], z1);    z1 = fmaf(v.w, wr[DD+d+3], z1);
        z2 = fmaf(v.x, wr[2*DD+d], z2);    z2 = fmaf(v.y, wr[2*DD+d+1], z2);
        z2 = fmaf(v.z, wr[2*DD+d+2], z2);  z2 = fmaf(v.w, wr[2*DD+d+3], z2);
    }

    const float r3 = 0.57735026918962576f; // 1/sqrt(3)
    float p[EE];
    float mx = -1e30f;
#pragma unroll
    for (int e = 0; e < EE; e++) {
        float s0 = (e & 4) ? z0 : -z0;   // itertools.product([-1,1]) order
        float s1 = (e & 2) ? z1 : -z1;
        float s2 = (e & 1) ? z2 : -z2;
        p[e] = (s0 + s1 + s2) * r3;
        mx = fmaxf(mx, p[e]);
    }
    float sum = 0.f;
#pragma unroll
    for (int e = 0; e < EE; e++) { p[e] = expf(p[e] - mx); sum += p[e]; }
    float inv_s = 1.f / sum;
#pragma unroll
    for (int e = 0; e < EE; e++) p[e] *= inv_s;

    int e1 = 0; float p1 = p[0];
#pragma unroll
    for (int e = 1; e < EE; e++) if (p[e] > p1) { p1 = p[e]; e1 = e; }
    int e2 = -1; float p2 = -1.f;
#pragma unroll
    for (int e = 0; e < EE; e++) if (e != e1 && p[e] > p2) { p2 = p[e]; e2 = e; }
    float inv_t = 1.f / (p1 + p2);
    top_e[2*n]   = e1;  top_g[2*n]   = p1 * inv_t;
    top_e[2*n+1] = e2;  top_g[2*n+1] = p2 * inv_t;
    atomicAdd(&counts[e1], 1);
    atomicAdd(&counts[e2], 1);

#pragma unroll
    for (int e = 0; e < EE; e++) atomicAdd(&lpsum[e], p[e]);
    __syncthreads();
    if (tid < EE) atomicAdd(&psum[tid], lpsum[tid]);
}

// ---------------------------------------------------------------------------
// 2. Scan counts -> padded offsets (128-aligned), cursor, aux loss
// ---------------------------------------------------------------------------
__global__ void scan_aux_kernel(const int* __restrict__ counts, const float* __restrict__ psum,
                                int* __restrict__ cursor, int* __restrict__ poffs,
                                float* __restrict__ out_aux)
{
    if (threadIdx.x == 0) {
        int run = 0;
        for (int e = 0; e < EE; e++) {
            poffs[e] = run;
            cursor[e] = run;
            run += ((counts[e] + 127) >> 7) << 7;   // pad each expert to 128
        }
        poffs[EE] = run;
        float s = 0.f;
        for (int e = 0; e < EE; e++) {
            float t = psum[e] * (1.f / NN) - (1.f / EE);
            s += t * t;
        }
        *out_aux = 0.01f * (s * (1.f / EE));
    }
}

// ---------------------------------------------------------------------------
// 3. Scatter tokens into padded compact per-expert rows; record inverse map
// ---------------------------------------------------------------------------
__global__ __launch_bounds__(256) void scatter_kernel(
    const int* __restrict__ top_e, int* __restrict__ cursor,
    int* __restrict__ row_tok, int* __restrict__ inv_row)
{
    int n = blockIdx.x * 256 + threadIdx.x;
#pragma unroll
    for (int k = 0; k < 2; k++) {
        int e = top_e[2*n + k];
        int pos = atomicAdd(&cursor[e], 1);
        row_tok[pos]    = n;
        inv_row[2*n+k]  = pos;
    }
}

// ---------------------------------------------------------------------------
// 3b. Gather+cast: xg[pr] = bf16(x[row_tok[pr]]); zero pad rows
// ---------------------------------------------------------------------------
__global__ __launch_bounds__(192) void gather_cast_kernel(
    const float* __restrict__ x, const int* __restrict__ counts,
    const int* __restrict__ poffs, const int* __restrict__ row_tok,
    unsigned short* __restrict__ xg)
{
    int t = threadIdx.x;
    int pr = blockIdx.x * 4 + t / 48;      // 4 rows / block, 48 threads / row
    int c0 = (t % 48) * 16;                // 16 elements / thread
    int e = 0;
#pragma unroll
    for (int i = 0; i < EE - 1; i++) if (pr >= poffs[i + 1]) e = i + 1;
    int local = pr - poffs[e];
    unsigned short* dst = xg + (size_t)pr * DD + c0;
    if (local < counts[e]) {
        int tok = row_tok[pr];
        const float4* sp = (const float4*)(x + (size_t)tok * DD + c0);
        alignas(16) unsigned short tmp[16];
#pragma unroll
        for (int j = 0; j < 4; j++) {
            float4 v = sp[j];
            tmp[4*j+0] = f2bf(v.x); tmp[4*j+1] = f2bf(v.y);
            tmp[4*j+2] = f2bf(v.z); tmp[4*j+3] = f2bf(v.w);
        }
        *(uint4*)dst       = *(uint4*)&tmp[0];
        *(uint4*)(dst + 8) = *(uint4*)&tmp[8];
    } else {
        uint4 z = {0, 0, 0, 0};
        *(uint4*)dst       = z;
        *(uint4*)(dst + 8) = z;
    }
}

// ---------------------------------------------------------------------------
// 4. Weight transpose + bf16 cast: W1(E,D,H)->w1t(E,H,D), W2(E,H,D)->w2t(E,D,H)
// ---------------------------------------------------------------------------
__global__ __launch_bounds__(256) void transpose_cast_kernel(
    const float* __restrict__ W1, const float* __restrict__ W2,
    unsigned short* __restrict__ w1t, unsigned short* __restrict__ w2t)
{
    int z = blockIdx.z, e = blockIdx.y, bx = blockIdx.x;
    const float* src; unsigned short* dst; int R, C, rt, ct;
    if (z == 0) { R = DD; C = HH; src = W1 + (size_t)e * R * C; dst = w1t + (size_t)e * R * C; }
    else        { R = HH; C = DD; src = W2 + (size_t)e * R * C; dst = w2t + (size_t)e * R * C; }
    rt = bx / (C / 64); ct = bx % (C / 64);
    int r0 = rt * 64, c0 = ct * 64;

    __shared__ unsigned short tile[64][66];
    int tid = threadIdx.x;
    int lr = tid >> 2, lc = (tid & 3) * 16;
    const float4* sp = (const float4*)(src + (size_t)(r0 + lr) * C + c0 + lc);
#pragma unroll
    for (int j = 0; j < 4; j++) {
        float4 v = sp[j];
        tile[lr][lc + 4*j + 0] = f2bf(v.x);
        tile[lr][lc + 4*j + 1] = f2bf(v.y);
        tile[lr][lc + 4*j + 2] = f2bf(v.z);
        tile[lr][lc + 4*j + 3] = f2bf(v.w);
    }
    __syncthreads();
    int oc = tid >> 2, orr = (tid & 3) * 16;
    alignas(16) unsigned short tmp[16];
#pragma unroll
    for (int j = 0; j < 16; j++) tmp[j] = tile[orr + j][oc];
    unsigned short* dp = dst + (size_t)(c0 + oc) * R + r0 + orr;
    *(uint4*)dp       = *(uint4*)&tmp[0];
    *(uint4*)(dp + 8) = *(uint4*)&tmp[8];
}

// ---------------------------------------------------------------------------
// 5. GEMM1: h = gelu(xg @ W1[e]^T-layout) -> bf16.
//    Double-buffered: prefetch tile kt+1 via global_load_lds before computing
//    tile kt; single __syncthreads per K-step (T3-min 2-phase).
// ---------------------------------------------------------------------------
__global__ __launch_bounds__(256) void gemm1_kernel(
    const unsigned short* __restrict__ xg, const unsigned short* __restrict__ w1t,
    unsigned short* __restrict__ h, const int* __restrict__ poffs)
{
    int t = blockIdx.x;
    if (t * 128 >= poffs[EE]) return;
    int e = 0;
#pragma unroll
    for (int i = 0; i < EE - 1; i++) if (t * 128 >= poffs[i + 1]) e = i + 1;
    int row0 = t * 128, n0 = blockIdx.y * 128;

    __shared__ alignas(16) unsigned short As[2][128][32];
    __shared__ alignas(16) unsigned short Bs[2][128][32];

    int tid = threadIdx.x;
    int w = tid >> 6, lane = tid & 63;
    int quad = lane >> 4, l15 = lane & 15;
    int wm = (w & 1) * 64, wn = (w >> 1) * 64;

    const unsigned short* abase = xg + (size_t)row0 * DD;
    const unsigned short* bbase = w1t + (size_t)e * HH * DD + (size_t)n0 * DD;

    // chunk c covers shorts [c*8, c*8+8): row = c>>2, k-part = (c&3)*8
    int c0 = w * 64 + lane, c1 = 256 + c0;
    const unsigned short* ga0 = abase + (c0 >> 2) * DD + (c0 & 3) * 8;
    const unsigned short* ga1 = abase + (c1 >> 2) * DD + (c1 & 3) * 8;
    const unsigned short* gb0 = bbase + (c0 >> 2) * DD + (c0 & 3) * 8;
    const unsigned short* gb1 = bbase + (c1 >> 2) * DD + (c1 & 3) * 8;
    int lofs0 = (w * 64) * 8;            // wave-uniform short offsets
    int lofs1 = (256 + w * 64) * 8;

    floatx4 acc[4][4];
#pragma unroll
    for (int i = 0; i < 4; i++)
#pragma unroll
        for (int j = 0; j < 4; j++)
#pragma unroll
            for (int r = 0; r < 4; r++) acc[i][j][r] = 0.f;

    const int NT = DD / 32;
    // prologue: stage tile 0 into buffer 0
    gld16(ga0, &As[0][0][0] + lofs0);
    gld16(ga1, &As[0][0][0] + lofs1);
    gld16(gb0, &Bs[0][0][0] + lofs0);
    gld16(gb1, &Bs[0][0][0] + lofs1);
    __syncthreads();

    for (int kt = 0; kt < NT; kt++) {
        int cur = kt & 1;
        if (kt + 1 < NT) {                 // prefetch next tile into other buf
            int k0 = (kt + 1) * 32;
            unsigned short* nA = &As[cur ^ 1][0][0];
            unsigned short* nB = &Bs[cur ^ 1][0][0];
            gld16(ga0 + k0, nA + lofs0);
            gld16(ga1 + k0, nA + lofs1);
            gld16(gb0 + k0, nB + lofs0);
            gld16(gb1 + k0, nB + lofs1);
        }
        short8 afr[4], bfr[4];
#pragma unroll
        for (int fm = 0; fm < 4; fm++) afr[fm] = *(const short8*)&As[cur][wm + fm*16 + l15][quad * 8];
#pragma unroll
        for (int fn = 0; fn < 4; fn++) bfr[fn] = *(const short8*)&Bs[cur][wn + fn*16 + l15][quad * 8];
#pragma unroll
        for (int fm = 0; fm < 4; fm++)
#pragma unroll
            for (int fn = 0; fn < 4; fn++)
                acc[fm][fn] = __builtin_amdgcn_mfma_f32_16x16x32_bf16(afr[fm], bfr[fn], acc[fm][fn], 0, 0, 0);
        __syncthreads();   // drains prefetch (vmcnt 0) + LDS reads, joins waves
    }

#pragma unroll
    for (int fm = 0; fm < 4; fm++)
#pragma unroll
        for (int r = 0; r < 4; r++) {
            int rt = wm + fm * 16 + quad * 4 + r;
            size_t hrow = (size_t)(row0 + rt) * HH;
#pragma unroll
            for (int fn = 0; fn < 4; fn++) {
                int col = n0 + wn + fn * 16 + l15;
                float v = acc[fm][fn][r];
                float g = 0.5f * v * (1.f + erff(v * 0.70710678118654752f));
                h[hrow + col] = f2bf(g);
            }
        }
}

// ---------------------------------------------------------------------------
// 6. GEMM2: ybuf[kz][row] = h @ W2[e] partial (K split in 2). No atomics:
//    plain f32 stores into compact ybuf; combine_kernel reduces per token.
// ---------------------------------------------------------------------------
__global__ __launch_bounds__(256) void gemm2_kernel(
    const unsigned short* __restrict__ h, const unsigned short* __restrict__ w2t,
    float* __restrict__ ybuf, const int* __restrict__ poffs)
{
    int t = blockIdx.x;
    if (t * 128 >= poffs[EE]) return;
    int e = 0;
#pragma unroll
    for (int i = 0; i < EE - 1; i++) if (t * 128 >= poffs[i + 1]) e = i + 1;
    int row0 = t * 128, n0 = blockIdx.y * 128;
    int kz = blockIdx.z;                  // K-split: [kz*1536, kz*1536+1536)

    __shared__ alignas(16) unsigned short As[2][128][32];
    __shared__ alignas(16) unsigned short Bs[2][128][32];

    int tid = threadIdx.x;
    int w = tid >> 6, lane = tid & 63;
    int quad = lane >> 4, l15 = lane & 15;
    int wm = (w & 1) * 64, wn = (w >> 1) * 64;

    const unsigned short* abase = h + (size_t)row0 * HH + kz * (HH / 2);
    const unsigned short* bbase = w2t + (size_t)e * DD * HH + (size_t)n0 * HH + kz * (HH / 2);

    int c0 = w * 64 + lane, c1 = 256 + c0;
    const unsigned short* ga0 = abase + (c0 >> 2) * HH + (c0 & 3) * 8;
    const unsigned short* ga1 = abase + (c1 >> 2) * HH + (c1 & 3) * 8;
    const unsigned short* gb0 = bbase + (c0 >> 2) * HH + (c0 & 3) * 8;
    const unsigned short* gb1 = bbase + (c1 >> 2) * HH + (c1 & 3) * 8;
    int lofs0 = (w * 64) * 8;
    int lofs1 = (256 + w * 64) * 8;

    floatx4 acc[4][4];
#pragma unroll
    for (int i = 0; i < 4; i++)
#pragma unroll
        for (int j = 0; j < 4; j++)
#pragma unroll
            for (int r = 0; r < 4; r++) acc[i][j][r] = 0.f;

    const int NT = (HH / 2) / 32;
    gld16(ga0, &As[0][0][0] + lofs0);
    gld16(ga1, &As[0][0][0] + lofs1);
    gld16(gb0, &Bs[0][0][0] + lofs0);
    gld16(gb1, &Bs[0][0][0] + lofs1);
    __syncthreads();

    for (int kt = 0; kt < NT; kt++) {
        int cur = kt & 1;
        if (kt + 1 < NT) {
            int k0 = (kt + 1) * 32;
            unsigned short* nA = &As[cur ^ 1][0][0];
            unsigned short* nB = &Bs[cur ^ 1][0][0];
            gld16(ga0 + k0, nA + lofs0);
            gld16(ga1 + k0, nA + lofs1);
            gld16(gb0 + k0, nB + lofs0);
            gld16(gb1 + k0, nB + lofs1);
        }
        short8 afr[4], bfr[4];
#pragma unroll
        for (int fm = 0; fm < 4; fm++) afr[fm] = *(const short8*)&As[cur][wm + fm*16 + l15][quad * 8];
#pragma unroll
        for (int fn = 0; fn < 4; fn++) bfr[fn] = *(const short8*)&Bs[cur][wn + fn*16 + l15][quad * 8];
#pragma unroll
        for (int fm = 0; fm < 4; fm++)
#pragma unroll
            for (int fn = 0; fn < 4; fn++)
                acc[fm][fn] = __builtin_amdgcn_mfma_f32_16x16x32_bf16(afr[fm], bfr[fn], acc[fm][fn], 0, 0, 0);
        __syncthreads();
    }

    float* yb = ybuf + (size_t)kz * PP * DD + (size_t)row0 * DD;
#pragma unroll
    for (int fm = 0; fm < 4; fm++)
#pragma unroll
        for (int r = 0; r < 4; r++) {
            int rt = wm + fm * 16 + quad * 4 + r;
            float* op = yb + (size_t)rt * DD + n0 + wn;
#pragma unroll
            for (int fn = 0; fn < 4; fn++)
                op[fn * 16 + l15] = acc[fm][fn][r];
        }
}

// ---------------------------------------------------------------------------
// 7. Combine: out[n] = g0*(y[0][r0]+y[1][r0]) + g1*(y[0][r1]+y[1][r1])
// ---------------------------------------------------------------------------
__global__ __launch_bounds__(192) void combine_kernel(
    const float* __restrict__ ybuf, const int* __restrict__ inv_row,
    const float* __restrict__ top_g, float* __restrict__ out)
{
    int n = blockIdx.x;
    int c = threadIdx.x * 4;
    int r0 = inv_row[2*n], r1 = inv_row[2*n+1];
    float g0 = top_g[2*n], g1 = top_g[2*n+1];
    const size_t S = (size_t)PP * DD;
    const float* y0 = ybuf + (size_t)r0 * DD + c;
    const float* y1 = ybuf + (size_t)r1 * DD + c;
    float4 a0 = *(const float4*)y0, b0 = *(const float4*)(y0 + S);
    float4 a1 = *(const float4*)y1, b1 = *(const float4*)(y1 + S);
    float4 o;
    o.x = g0 * (a0.x + b0.x) + g1 * (a1.x + b1.x);
    o.y = g0 * (a0.y + b0.y) + g1 * (a1.y + b1.y);
    o.z = g0 * (a0.z + b0.z) + g1 * (a1.z + b1.z);
    o.w = g0 * (a0.w + b0.w) + g1 * (a1.w + b1.w);
    *(float4*)(out + (size_t)n * DD + c) = o;
}

// ---------------------------------------------------------------------------
extern "C" void kernel_launch(void* const* d_in, const int* in_sizes, int n_in,
                              void* d_out, int out_size, void* d_ws, size_t ws_size,
                              hipStream_t stream)
{
    const float* x  = (const float*)d_in[0];
    const float* Wr = (const float*)d_in[1];
    const float* W1 = (const float*)d_in[2];
    const float* W2 = (const float*)d_in[3];
    float* out = (float*)d_out;

    char* ws = (char*)d_ws;
    int*   counts   = (int*)(ws + 0);        // 8
    int*   cursor   = (int*)(ws + 32);       // 8
    float* psum     = (float*)(ws + 64);     // 8
    int*   poffs    = (int*)(ws + 96);       // 9
    int*   top_e    = (int*)(ws + 1024);                       // 4096 ints
    float* top_g    = (float*)(ws + 1024 + 16384);             // 4096 floats
    int*   row_tok  = (int*)(ws + 1024 + 2 * 16384);           // PP ints
    int*   inv_row  = (int*)(ws + 1024 + 2 * 16384 + PP * 4);  // 4096 ints
    size_t off = (size_t)(1024 + 2 * 16384 + PP * 4 + 16384 + 255) & ~(size_t)255;
    unsigned short* xg  = (unsigned short*)(ws + off); off += (size_t)PP * DD * 2;
    unsigned short* hbf = (unsigned short*)(ws + off); off += (size_t)PP * HH * 2;
    unsigned short* w1t = (unsigned short*)(ws + off); off += (size_t)EE * DD * HH * 2;
    unsigned short* w2t = (unsigned short*)(ws + off);
    // ybuf (2*PP*DD f32 = 31.5MB) aliases w1t (37.7MB): w1t is dead after
    // gemm1, rewritten by transpose_cast at the start of the next launch.
    float* ybuf = (float*)w1t;

    hipMemsetAsync(ws, 0, 96, stream);   // counts + cursor + psum

    transpose_cast_kernel<<<dim3(576, EE, 2), 256, 0, stream>>>(W1, W2, w1t, w2t);
    routing_kernel<<<dim3(NN / 256), 256, 0, stream>>>(x, Wr, counts, psum, top_e, top_g);
    scan_aux_kernel<<<1, 64, 0, stream>>>(counts, psum, cursor, poffs, out + (size_t)NN * DD);
    scatter_kernel<<<dim3(NN / 256), 256, 0, stream>>>(top_e, cursor, row_tok, inv_row);
    gather_cast_kernel<<<dim3(PP / 4), 192, 0, stream>>>(x, counts, poffs, row_tok, xg);
    gemm1_kernel<<<dim3(PT, HH / 128), 256, 0, stream>>>(xg, w1t, hbf, poffs);
    gemm2_kernel<<<dim3(PT, DD / 128, 2), 256, 0, stream>>>(hbf, w2t, ybuf, poffs);
    combine_kernel<<<dim3(NN), 192, 0, stream>>>(ybuf, inv_row, top_g, out);
}

// Round 3
// 349.328 us; speedup vs baseline: 1.3464x; 1.0971x over previous
//
#include <hip/hip_runtime.h>
#include <hip/hip_bf16.h>
#include <math.h>

#define DD 768
#define HH 3072
#define EE 8
#define NN 2048   // B*T tokens
#define PP 5120   // max padded compact rows (4096 + 8*128)
#define PT 40     // max padded m-tiles (PP/128)

typedef __attribute__((ext_vector_type(8))) short short8;   // 8 bf16 MFMA operand
typedef __attribute__((ext_vector_type(4))) float floatx4;  // MFMA accumulator

typedef const __attribute__((address_space(1))) void gas_void;
typedef __attribute__((address_space(3))) void las_void;

__device__ __forceinline__ void gld16(const void* g, void* l) {
    // async global->LDS DMA, 16B/lane; LDS dest = wave-uniform base + lane*16
    __builtin_amdgcn_global_load_lds((gas_void*)g, (las_void*)l, 16, 0, 0);
}

__device__ __forceinline__ unsigned short f2bf(float f) {
    union { float f; unsigned int u; } v; v.f = f;
    unsigned int u = v.u;
    u += 0x7fffu + ((u >> 16) & 1u);   // RNE (inputs finite)
    return (unsigned short)(u >> 16);
}

// ---------------------------------------------------------------------------
// 1. Routing: 16 lanes per token (D split 48 elems/lane), shfl reduce,
//    lane 0 does softmax/top-2. Grid 128 blocks -> all CUs engaged.
// ---------------------------------------------------------------------------
__global__ __launch_bounds__(256) void routing_kernel(
    const float* __restrict__ x, const float* __restrict__ Wr,
    int* __restrict__ counts, float* __restrict__ psum,
    int* __restrict__ top_e, float* __restrict__ top_g)
{
    __shared__ float wr[3 * DD];
    __shared__ float lpsum[EE];
    int tid = threadIdx.x;
    for (int i = tid; i < 3 * DD; i += 256) wr[i] = Wr[i];
    if (tid < EE) lpsum[tid] = 0.f;
    __syncthreads();

    int sub = tid & 15;                    // lane within 16-lane token group
    int n = blockIdx.x * 16 + (tid >> 4);  // 16 tokens per block
    const float* xr = x + (size_t)n * DD;
    float z0 = 0.f, z1 = 0.f, z2 = 0.f;
#pragma unroll
    for (int i = 0; i < DD / 64; i++) {
        int d = i * 64 + sub * 4;
        float4 v = *(const float4*)(xr + d);
        z0 = fmaf(v.x, wr[d], z0);         z0 = fmaf(v.y, wr[d+1], z0);
        z0 = fmaf(v.z, wr[d+2], z0);       z0 = fmaf(v.w, wr[d+3], z0);
        z1 = fmaf(v.x, wr[DD+d], z1);      z1 = fmaf(v.y, wr[DD+d+1], z1);
        z1 = fmaf(v.z, wr[DD+d+2], z1);    z1 = fmaf(v.w, wr[DD+d+3], z1);
        z2 = fmaf(v.x, wr[2*DD+d], z2);    z2 = fmaf(v.y, wr[2*DD+d+1], z2);
        z2 = fmaf(v.z, wr[2*DD+d+2], z2);  z2 = fmaf(v.w, wr[2*DD+d+3], z2);
    }
#pragma unroll
    for (int m = 8; m; m >>= 1) {
        z0 += __shfl_xor(z0, m, 16);
        z1 += __shfl_xor(z1, m, 16);
        z2 += __shfl_xor(z2, m, 16);
    }

    if (sub == 0) {
        const float r3 = 0.57735026918962576f; // 1/sqrt(3)
        float p[EE];
        float mx = -1e30f;
#pragma unroll
        for (int e = 0; e < EE; e++) {
            float s0 = (e & 4) ? z0 : -z0;   // itertools.product([-1,1]) order
            float s1 = (e & 2) ? z1 : -z1;
            float s2 = (e & 1) ? z2 : -z2;
            p[e] = (s0 + s1 + s2) * r3;
            mx = fmaxf(mx, p[e]);
        }
        float sum = 0.f;
#pragma unroll
        for (int e = 0; e < EE; e++) { p[e] = expf(p[e] - mx); sum += p[e]; }
        float inv_s = 1.f / sum;
#pragma unroll
        for (int e = 0; e < EE; e++) p[e] *= inv_s;

        int e1 = 0; float p1 = p[0];
#pragma unroll
        for (int e = 1; e < EE; e++) if (p[e] > p1) { p1 = p[e]; e1 = e; }
        int e2 = -1; float p2 = -1.f;
#pragma unroll
        for (int e = 0; e < EE; e++) if (e != e1 && p[e] > p2) { p2 = p[e]; e2 = e; }
        float inv_t = 1.f / (p1 + p2);
        top_e[2*n]   = e1;  top_g[2*n]   = p1 * inv_t;
        top_e[2*n+1] = e2;  top_g[2*n+1] = p2 * inv_t;
        atomicAdd(&counts[e1], 1);
        atomicAdd(&counts[e2], 1);
#pragma unroll
        for (int e = 0; e < EE; e++) atomicAdd(&lpsum[e], p[e]);
    }
    __syncthreads();
    if (tid < EE) atomicAdd(&psum[tid], lpsum[tid]);
}

// ---------------------------------------------------------------------------
// 2. Scan counts -> padded offsets (128-aligned), cursor, aux loss
// ---------------------------------------------------------------------------
__global__ void scan_aux_kernel(const int* __restrict__ counts, const float* __restrict__ psum,
                                int* __restrict__ cursor, int* __restrict__ poffs,
                                float* __restrict__ out_aux)
{
    if (threadIdx.x == 0) {
        int run = 0;
        for (int e = 0; e < EE; e++) {
            poffs[e] = run;
            cursor[e] = run;
            run += ((counts[e] + 127) >> 7) << 7;   // pad each expert to 128
        }
        poffs[EE] = run;
        float s = 0.f;
        for (int e = 0; e < EE; e++) {
            float t = psum[e] * (1.f / NN) - (1.f / EE);
            s += t * t;
        }
        *out_aux = 0.01f * (s * (1.f / EE));
    }
}

// ---------------------------------------------------------------------------
// 3. Scatter tokens into padded compact per-expert rows; record inverse map
// ---------------------------------------------------------------------------
__global__ __launch_bounds__(256) void scatter_kernel(
    const int* __restrict__ top_e, int* __restrict__ cursor,
    int* __restrict__ row_tok, int* __restrict__ inv_row)
{
    int n = blockIdx.x * 256 + threadIdx.x;
#pragma unroll
    for (int k = 0; k < 2; k++) {
        int e = top_e[2*n + k];
        int pos = atomicAdd(&cursor[e], 1);
        row_tok[pos]    = n;
        inv_row[2*n+k]  = pos;
    }
}

// ---------------------------------------------------------------------------
// 3b. Gather+cast: xg[pr] = bf16(x[row_tok[pr]]); zero pad rows
// ---------------------------------------------------------------------------
__global__ __launch_bounds__(192) void gather_cast_kernel(
    const float* __restrict__ x, const int* __restrict__ counts,
    const int* __restrict__ poffs, const int* __restrict__ row_tok,
    unsigned short* __restrict__ xg)
{
    int t = threadIdx.x;
    int pr = blockIdx.x * 4 + t / 48;      // 4 rows / block, 48 threads / row
    int c0 = (t % 48) * 16;                // 16 elements / thread
    int e = 0;
#pragma unroll
    for (int i = 0; i < EE - 1; i++) if (pr >= poffs[i + 1]) e = i + 1;
    int local = pr - poffs[e];
    unsigned short* dst = xg + (size_t)pr * DD + c0;
    if (local < counts[e]) {
        int tok = row_tok[pr];
        const float4* sp = (const float4*)(x + (size_t)tok * DD + c0);
        alignas(16) unsigned short tmp[16];
#pragma unroll
        for (int j = 0; j < 4; j++) {
            float4 v = sp[j];
            tmp[4*j+0] = f2bf(v.x); tmp[4*j+1] = f2bf(v.y);
            tmp[4*j+2] = f2bf(v.z); tmp[4*j+3] = f2bf(v.w);
        }
        *(uint4*)dst       = *(uint4*)&tmp[0];
        *(uint4*)(dst + 8) = *(uint4*)&tmp[8];
    } else {
        uint4 z = {0, 0, 0, 0};
        *(uint4*)dst       = z;
        *(uint4*)(dst + 8) = z;
    }
}

// ---------------------------------------------------------------------------
// 4. Weight transpose + bf16 cast, pipelined strips: each block owns 4
//    column-tiles; register prefetch of tile i+1 overlaps the LDS column-read
//    and global store of tile i (plain VGPR loads -> no vmcnt drain at barrier).
// ---------------------------------------------------------------------------
__global__ __launch_bounds__(256) void transpose_cast_kernel(
    const float* __restrict__ W1, const float* __restrict__ W2,
    unsigned short* __restrict__ w1t, unsigned short* __restrict__ w2t)
{
    int z = blockIdx.z, e = blockIdx.y, bx = blockIdx.x;
    const float* src; unsigned short* dst; int R, C, SC;
    if (z == 0) { R = DD; C = HH; SC = 12; src = W1 + (size_t)e * R * C; dst = w1t + (size_t)e * R * C; }
    else        { R = HH; C = DD; SC = 3;  src = W2 + (size_t)e * R * C; dst = w2t + (size_t)e * R * C; }
    int rt = bx / SC, cs = bx % SC;
    int r0 = rt * 64, cbase = cs * 256;    // strip = 4 tiles of 64 cols

    __shared__ unsigned short tile[64][66];
    int tid = threadIdx.x;
    int lr = tid >> 2, lc = (tid & 3) * 16;     // load: row lr, 16 cols at lc
    int oc = tid >> 2, orr = (tid & 3) * 16;    // store: col oc, 16 rows at orr
    const float* srow = src + (size_t)(r0 + lr) * C + lc;

    float4 v0, v1, v2, v3;
    {
        const float4* sp = (const float4*)(srow + cbase);
        v0 = sp[0]; v1 = sp[1]; v2 = sp[2]; v3 = sp[3];
    }
#pragma unroll
    for (int i = 0; i < 4; i++) {
        int c0 = cbase + i * 64;
        if (i) __syncthreads();           // prior col-reads done before overwrite
        tile[lr][lc+ 0]=f2bf(v0.x); tile[lr][lc+ 1]=f2bf(v0.y);
        tile[lr][lc+ 2]=f2bf(v0.z); tile[lr][lc+ 3]=f2bf(v0.w);
        tile[lr][lc+ 4]=f2bf(v1.x); tile[lr][lc+ 5]=f2bf(v1.y);
        tile[lr][lc+ 6]=f2bf(v1.z); tile[lr][lc+ 7]=f2bf(v1.w);
        tile[lr][lc+ 8]=f2bf(v2.x); tile[lr][lc+ 9]=f2bf(v2.y);
        tile[lr][lc+10]=f2bf(v2.z); tile[lr][lc+11]=f2bf(v2.w);
        tile[lr][lc+12]=f2bf(v3.x); tile[lr][lc+13]=f2bf(v3.y);
        tile[lr][lc+14]=f2bf(v3.z); tile[lr][lc+15]=f2bf(v3.w);
        if (i < 3) {                      // prefetch next tile (flies during
            const float4* sp = (const float4*)(srow + c0 + 64);   // read+store)
            v0 = sp[0]; v1 = sp[1]; v2 = sp[2]; v3 = sp[3];
        }
        __syncthreads();
        alignas(16) unsigned short tmp[16];
#pragma unroll
        for (int j = 0; j < 16; j++) tmp[j] = tile[orr + j][oc];
        unsigned short* dp = dst + (size_t)(c0 + oc) * R + r0 + orr;
        *(uint4*)dp       = *(uint4*)&tmp[0];
        *(uint4*)(dp + 8) = *(uint4*)&tmp[8];
    }
}

// ---------------------------------------------------------------------------
// 5. GEMM1: h = gelu(xg @ W1[e]^T-layout) -> bf16.
//    Double-buffered: prefetch tile kt+1 via global_load_lds before computing
//    tile kt; single __syncthreads per K-step (T3-min 2-phase).
// ---------------------------------------------------------------------------
__global__ __launch_bounds__(256) void gemm1_kernel(
    const unsigned short* __restrict__ xg, const unsigned short* __restrict__ w1t,
    unsigned short* __restrict__ h, const int* __restrict__ poffs)
{
    int t = blockIdx.x;
    if (t * 128 >= poffs[EE]) return;
    int e = 0;
#pragma unroll
    for (int i = 0; i < EE - 1; i++) if (t * 128 >= poffs[i + 1]) e = i + 1;
    int row0 = t * 128, n0 = blockIdx.y * 128;

    __shared__ alignas(16) unsigned short As[2][128][32];
    __shared__ alignas(16) unsigned short Bs[2][128][32];

    int tid = threadIdx.x;
    int w = tid >> 6, lane = tid & 63;
    int quad = lane >> 4, l15 = lane & 15;
    int wm = (w & 1) * 64, wn = (w >> 1) * 64;

    const unsigned short* abase = xg + (size_t)row0 * DD;
    const unsigned short* bbase = w1t + (size_t)e * HH * DD + (size_t)n0 * DD;

    // chunk c covers shorts [c*8, c*8+8): row = c>>2, k-part = (c&3)*8
    int c0 = w * 64 + lane, c1 = 256 + c0;
    const unsigned short* ga0 = abase + (c0 >> 2) * DD + (c0 & 3) * 8;
    const unsigned short* ga1 = abase + (c1 >> 2) * DD + (c1 & 3) * 8;
    const unsigned short* gb0 = bbase + (c0 >> 2) * DD + (c0 & 3) * 8;
    const unsigned short* gb1 = bbase + (c1 >> 2) * DD + (c1 & 3) * 8;
    int lofs0 = (w * 64) * 8;            // wave-uniform short offsets
    int lofs1 = (256 + w * 64) * 8;

    floatx4 acc[4][4];
#pragma unroll
    for (int i = 0; i < 4; i++)
#pragma unroll
        for (int j = 0; j < 4; j++)
#pragma unroll
            for (int r = 0; r < 4; r++) acc[i][j][r] = 0.f;

    const int NT = DD / 32;
    // prologue: stage tile 0 into buffer 0
    gld16(ga0, &As[0][0][0] + lofs0);
    gld16(ga1, &As[0][0][0] + lofs1);
    gld16(gb0, &Bs[0][0][0] + lofs0);
    gld16(gb1, &Bs[0][0][0] + lofs1);
    __syncthreads();

    for (int kt = 0; kt < NT; kt++) {
        int cur = kt & 1;
        if (kt + 1 < NT) {                 // prefetch next tile into other buf
            int k0 = (kt + 1) * 32;
            unsigned short* nA = &As[cur ^ 1][0][0];
            unsigned short* nB = &Bs[cur ^ 1][0][0];
            gld16(ga0 + k0, nA + lofs0);
            gld16(ga1 + k0, nA + lofs1);
            gld16(gb0 + k0, nB + lofs0);
            gld16(gb1 + k0, nB + lofs1);
        }
        short8 afr[4], bfr[4];
#pragma unroll
        for (int fm = 0; fm < 4; fm++) afr[fm] = *(const short8*)&As[cur][wm + fm*16 + l15][quad * 8];
#pragma unroll
        for (int fn = 0; fn < 4; fn++) bfr[fn] = *(const short8*)&Bs[cur][wn + fn*16 + l15][quad * 8];
#pragma unroll
        for (int fm = 0; fm < 4; fm++)
#pragma unroll
            for (int fn = 0; fn < 4; fn++)
                acc[fm][fn] = __builtin_amdgcn_mfma_f32_16x16x32_bf16(afr[fm], bfr[fn], acc[fm][fn], 0, 0, 0);
        __syncthreads();   // drains prefetch (vmcnt 0) + LDS reads, joins waves
    }

#pragma unroll
    for (int fm = 0; fm < 4; fm++)
#pragma unroll
        for (int r = 0; r < 4; r++) {
            int rt = wm + fm * 16 + quad * 4 + r;
            size_t hrow = (size_t)(row0 + rt) * HH;
#pragma unroll
            for (int fn = 0; fn < 4; fn++) {
                int col = n0 + wn + fn * 16 + l15;
                float v = acc[fm][fn][r];
                float g = 0.5f * v * (1.f + erff(v * 0.70710678118654752f));
                h[hrow + col] = f2bf(g);
            }
        }
}

// ---------------------------------------------------------------------------
// 6. GEMM2: ybuf[kz][row] = h @ W2[e] partial (K split in 2). No atomics:
//    plain f32 stores into compact ybuf; combine_kernel reduces per token.
// ---------------------------------------------------------------------------
__global__ __launch_bounds__(256) void gemm2_kernel(
    const unsigned short* __restrict__ h, const unsigned short* __restrict__ w2t,
    float* __restrict__ ybuf, const int* __restrict__ poffs)
{
    int t = blockIdx.x;
    if (t * 128 >= poffs[EE]) return;
    int e = 0;
#pragma unroll
    for (int i = 0; i < EE - 1; i++) if (t * 128 >= poffs[i + 1]) e = i + 1;
    int row0 = t * 128, n0 = blockIdx.y * 128;
    int kz = blockIdx.z;                  // K-split: [kz*1536, kz*1536+1536)

    __shared__ alignas(16) unsigned short As[2][128][32];
    __shared__ alignas(16) unsigned short Bs[2][128][32];

    int tid = threadIdx.x;
    int w = tid >> 6, lane = tid & 63;
    int quad = lane >> 4, l15 = lane & 15;
    int wm = (w & 1) * 64, wn = (w >> 1) * 64;

    const unsigned short* abase = h + (size_t)row0 * HH + kz * (HH / 2);
    const unsigned short* bbase = w2t + (size_t)e * DD * HH + (size_t)n0 * HH + kz * (HH / 2);

    int c0 = w * 64 + lane, c1 = 256 + c0;
    const unsigned short* ga0 = abase + (c0 >> 2) * HH + (c0 & 3) * 8;
    const unsigned short* ga1 = abase + (c1 >> 2) * HH + (c1 & 3) * 8;
    const unsigned short* gb0 = bbase + (c0 >> 2) * HH + (c0 & 3) * 8;
    const unsigned short* gb1 = bbase + (c1 >> 2) * HH + (c1 & 3) * 8;
    int lofs0 = (w * 64) * 8;
    int lofs1 = (256 + w * 64) * 8;

    floatx4 acc[4][4];
#pragma unroll
    for (int i = 0; i < 4; i++)
#pragma unroll
        for (int j = 0; j < 4; j++)
#pragma unroll
            for (int r = 0; r < 4; r++) acc[i][j][r] = 0.f;

    const int NT = (HH / 2) / 32;
    gld16(ga0, &As[0][0][0] + lofs0);
    gld16(ga1, &As[0][0][0] + lofs1);
    gld16(gb0, &Bs[0][0][0] + lofs0);
    gld16(gb1, &Bs[0][0][0] + lofs1);
    __syncthreads();

    for (int kt = 0; kt < NT; kt++) {
        int cur = kt & 1;
        if (kt + 1 < NT) {
            int k0 = (kt + 1) * 32;
            unsigned short* nA = &As[cur ^ 1][0][0];
            unsigned short* nB = &Bs[cur ^ 1][0][0];
            gld16(ga0 + k0, nA + lofs0);
            gld16(ga1 + k0, nA + lofs1);
            gld16(gb0 + k0, nB + lofs0);
            gld16(gb1 + k0, nB + lofs1);
        }
        short8 afr[4], bfr[4];
#pragma unroll
        for (int fm = 0; fm < 4; fm++) afr[fm] = *(const short8*)&As[cur][wm + fm*16 + l15][quad * 8];
#pragma unroll
        for (int fn = 0; fn < 4; fn++) bfr[fn] = *(const short8*)&Bs[cur][wn + fn*16 + l15][quad * 8];
#pragma unroll
        for (int fm = 0; fm < 4; fm++)
#pragma unroll
            for (int fn = 0; fn < 4; fn++)
                acc[fm][fn] = __builtin_amdgcn_mfma_f32_16x16x32_bf16(afr[fm], bfr[fn], acc[fm][fn], 0, 0, 0);
        __syncthreads();
    }

    float* yb = ybuf + (size_t)kz * PP * DD + (size_t)row0 * DD;
#pragma unroll
    for (int fm = 0; fm < 4; fm++)
#pragma unroll
        for (int r = 0; r < 4; r++) {
            int rt = wm + fm * 16 + quad * 4 + r;
            float* op = yb + (size_t)rt * DD + n0 + wn;
#pragma unroll
            for (int fn = 0; fn < 4; fn++)
                op[fn * 16 + l15] = acc[fm][fn][r];
        }
}

// ---------------------------------------------------------------------------
// 7. Combine: out[n] = g0*(y[0][r0]+y[1][r0]) + g1*(y[0][r1]+y[1][r1])
// ---------------------------------------------------------------------------
__global__ __launch_bounds__(192) void combine_kernel(
    const float* __restrict__ ybuf, const int* __restrict__ inv_row,
    const float* __restrict__ top_g, float* __restrict__ out)
{
    int n = blockIdx.x;
    int c = threadIdx.x * 4;
    int r0 = inv_row[2*n], r1 = inv_row[2*n+1];
    float g0 = top_g[2*n], g1 = top_g[2*n+1];
    const size_t S = (size_t)PP * DD;
    const float* y0 = ybuf + (size_t)r0 * DD + c;
    const float* y1 = ybuf + (size_t)r1 * DD + c;
    float4 a0 = *(const float4*)y0, b0 = *(const float4*)(y0 + S);
    float4 a1 = *(const float4*)y1, b1 = *(const float4*)(y1 + S);
    float4 o;
    o.x = g0 * (a0.x + b0.x) + g1 * (a1.x + b1.x);
    o.y = g0 * (a0.y + b0.y) + g1 * (a1.y + b1.y);
    o.z = g0 * (a0.z + b0.z) + g1 * (a1.z + b1.z);
    o.w = g0 * (a0.w + b0.w) + g1 * (a1.w + b1.w);
    *(float4*)(out + (size_t)n * DD + c) = o;
}

// ---------------------------------------------------------------------------
extern "C" void kernel_launch(void* const* d_in, const int* in_sizes, int n_in,
                              void* d_out, int out_size, void* d_ws, size_t ws_size,
                              hipStream_t stream)
{
    const float* x  = (const float*)d_in[0];
    const float* Wr = (const float*)d_in[1];
    const float* W1 = (const float*)d_in[2];
    const float* W2 = (const float*)d_in[3];
    float* out = (float*)d_out;

    char* ws = (char*)d_ws;
    int*   counts   = (int*)(ws + 0);        // 8
    int*   cursor   = (int*)(ws + 32);       // 8
    float* psum     = (float*)(ws + 64);     // 8
    int*   poffs    = (int*)(ws + 96);       // 9
    int*   top_e    = (int*)(ws + 1024);                       // 4096 ints
    float* top_g    = (float*)(ws + 1024 + 16384);             // 4096 floats
    int*   row_tok  = (int*)(ws + 1024 + 2 * 16384);           // PP ints
    int*   inv_row  = (int*)(ws + 1024 + 2 * 16384 + PP * 4);  // 4096 ints
    size_t off = (size_t)(1024 + 2 * 16384 + PP * 4 + 16384 + 255) & ~(size_t)255;
    unsigned short* xg  = (unsigned short*)(ws + off); off += (size_t)PP * DD * 2;
    unsigned short* hbf = (unsigned short*)(ws + off); off += (size_t)PP * HH * 2;
    unsigned short* w1t = (unsigned short*)(ws + off); off += (size_t)EE * DD * HH * 2;
    unsigned short* w2t = (unsigned short*)(ws + off);
    // ybuf (2*PP*DD f32 = 31.5MB) aliases w1t (37.7MB): w1t is dead after
    // gemm1, rewritten by transpose_cast at the start of the next launch.
    float* ybuf = (float*)w1t;

    hipMemsetAsync(ws, 0, 96, stream);   // counts + cursor + psum

    transpose_cast_kernel<<<dim3(144, EE, 2), 256, 0, stream>>>(W1, W2, w1t, w2t);
    routing_kernel<<<dim3(NN / 16), 256, 0, stream>>>(x, Wr, counts, psum, top_e, top_g);
    scan_aux_kernel<<<1, 64, 0, stream>>>(counts, psum, cursor, poffs, out + (size_t)NN * DD);
    scatter_kernel<<<dim3(NN / 256), 256, 0, stream>>>(top_e, cursor, row_tok, inv_row);
    gather_cast_kernel<<<dim3(PP / 4), 192, 0, stream>>>(x, counts, poffs, row_tok, xg);
    gemm1_kernel<<<dim3(PT, HH / 128), 256, 0, stream>>>(xg, w1t, hbf, poffs);
    gemm2_kernel<<<dim3(PT, DD / 128, 2), 256, 0, stream>>>(hbf, w2t, ybuf, poffs);
    combine_kernel<<<dim3(NN), 192, 0, stream>>>(ybuf, inv_row, top_g, out);
}

// Round 4
// 347.199 us; speedup vs baseline: 1.3547x; 1.0061x over previous
//
#include <hip/hip_runtime.h>
#include <hip/hip_bf16.h>
#include <math.h>

#define DD 768
#define HH 3072
#define EE 8
#define NN 2048   // B*T tokens
#define PP 5120   // max padded compact rows (4096 + 8*128)
#define PT 40     // max padded m-tiles (PP/128)

typedef __attribute__((ext_vector_type(8))) short short8;   // 8 bf16 MFMA operand
typedef __attribute__((ext_vector_type(4))) float floatx4;  // MFMA accumulator

typedef const __attribute__((address_space(1))) void gas_void;
typedef __attribute__((address_space(3))) void las_void;

__device__ __forceinline__ void gld16(const void* g, void* l) {
    // async global->LDS DMA, 16B/lane; LDS dest = wave-uniform base + lane*16
    __builtin_amdgcn_global_load_lds((gas_void*)g, (las_void*)l, 16, 0, 0);
}

__device__ __forceinline__ unsigned short f2bf(float f) {
    union { float f; unsigned int u; } v; v.f = f;
    unsigned int u = v.u;
    u += 0x7fffu + ((u >> 16) & 1u);   // RNE (inputs finite)
    return (unsigned short)(u >> 16);
}

// ---------------------------------------------------------------------------
// 1. Routing: 16 lanes per token (D split 48 elems/lane), shfl reduce,
//    lane 0 does softmax/top-2. Grid 128 blocks -> all CUs engaged.
// ---------------------------------------------------------------------------
__global__ __launch_bounds__(256) void routing_kernel(
    const float* __restrict__ x, const float* __restrict__ Wr,
    int* __restrict__ counts, float* __restrict__ psum,
    int* __restrict__ top_e, float* __restrict__ top_g)
{
    __shared__ float wr[3 * DD];
    __shared__ float lpsum[EE];
    int tid = threadIdx.x;
    for (int i = tid; i < 3 * DD; i += 256) wr[i] = Wr[i];
    if (tid < EE) lpsum[tid] = 0.f;
    __syncthreads();

    int sub = tid & 15;                    // lane within 16-lane token group
    int n = blockIdx.x * 16 + (tid >> 4);  // 16 tokens per block
    const float* xr = x + (size_t)n * DD;
    float z0 = 0.f, z1 = 0.f, z2 = 0.f;
#pragma unroll
    for (int i = 0; i < DD / 64; i++) {
        int d = i * 64 + sub * 4;
        float4 v = *(const float4*)(xr + d);
        z0 = fmaf(v.x, wr[d], z0);         z0 = fmaf(v.y, wr[d+1], z0);
        z0 = fmaf(v.z, wr[d+2], z0);       z0 = fmaf(v.w, wr[d+3], z0);
        z1 = fmaf(v.x, wr[DD+d], z1);      z1 = fmaf(v.y, wr[DD+d+1], z1);
        z1 = fmaf(v.z, wr[DD+d+2], z1);    z1 = fmaf(v.w, wr[DD+d+3], z1);
        z2 = fmaf(v.x, wr[2*DD+d], z2);    z2 = fmaf(v.y, wr[2*DD+d+1], z2);
        z2 = fmaf(v.z, wr[2*DD+d+2], z2);  z2 = fmaf(v.w, wr[2*DD+d+3], z2);
    }
#pragma unroll
    for (int m = 8; m; m >>= 1) {
        z0 += __shfl_xor(z0, m, 16);
        z1 += __shfl_xor(z1, m, 16);
        z2 += __shfl_xor(z2, m, 16);
    }

    if (sub == 0) {
        const float r3 = 0.57735026918962576f; // 1/sqrt(3)
        float p[EE];
        float mx = -1e30f;
#pragma unroll
        for (int e = 0; e < EE; e++) {
            float s0 = (e & 4) ? z0 : -z0;   // itertools.product([-1,1]) order
            float s1 = (e & 2) ? z1 : -z1;
            float s2 = (e & 1) ? z2 : -z2;
            p[e] = (s0 + s1 + s2) * r3;
            mx = fmaxf(mx, p[e]);
        }
        float sum = 0.f;
#pragma unroll
        for (int e = 0; e < EE; e++) { p[e] = expf(p[e] - mx); sum += p[e]; }
        float inv_s = 1.f / sum;
#pragma unroll
        for (int e = 0; e < EE; e++) p[e] *= inv_s;

        int e1 = 0; float p1 = p[0];
#pragma unroll
        for (int e = 1; e < EE; e++) if (p[e] > p1) { p1 = p[e]; e1 = e; }
        int e2 = -1; float p2 = -1.f;
#pragma unroll
        for (int e = 0; e < EE; e++) if (e != e1 && p[e] > p2) { p2 = p[e]; e2 = e; }
        float inv_t = 1.f / (p1 + p2);
        top_e[2*n]   = e1;  top_g[2*n]   = p1 * inv_t;
        top_e[2*n+1] = e2;  top_g[2*n+1] = p2 * inv_t;
        atomicAdd(&counts[e1], 1);
        atomicAdd(&counts[e2], 1);
#pragma unroll
        for (int e = 0; e < EE; e++) atomicAdd(&lpsum[e], p[e]);
    }
    __syncthreads();
    if (tid < EE) atomicAdd(&psum[tid], lpsum[tid]);
}

// ---------------------------------------------------------------------------
// 2. Scan counts -> padded offsets (128-aligned), cursor, aux loss
// ---------------------------------------------------------------------------
__global__ void scan_aux_kernel(const int* __restrict__ counts, const float* __restrict__ psum,
                                int* __restrict__ cursor, int* __restrict__ poffs,
                                float* __restrict__ out_aux)
{
    if (threadIdx.x == 0) {
        int run = 0;
        for (int e = 0; e < EE; e++) {
            poffs[e] = run;
            cursor[e] = run;
            run += ((counts[e] + 127) >> 7) << 7;   // pad each expert to 128
        }
        poffs[EE] = run;
        float s = 0.f;
        for (int e = 0; e < EE; e++) {
            float t = psum[e] * (1.f / NN) - (1.f / EE);
            s += t * t;
        }
        *out_aux = 0.01f * (s * (1.f / EE));
    }
}

// ---------------------------------------------------------------------------
// 3. Scatter tokens into padded compact per-expert rows; record inverse map
// ---------------------------------------------------------------------------
__global__ __launch_bounds__(256) void scatter_kernel(
    const int* __restrict__ top_e, int* __restrict__ cursor,
    int* __restrict__ row_tok, int* __restrict__ inv_row)
{
    int n = blockIdx.x * 256 + threadIdx.x;
#pragma unroll
    for (int k = 0; k < 2; k++) {
        int e = top_e[2*n + k];
        int pos = atomicAdd(&cursor[e], 1);
        row_tok[pos]    = n;
        inv_row[2*n+k]  = pos;
    }
}

// ---------------------------------------------------------------------------
// 3b. Gather+cast: xg[pr] = bf16(x[row_tok[pr]]); zero pad rows
// ---------------------------------------------------------------------------
__global__ __launch_bounds__(192) void gather_cast_kernel(
    const float* __restrict__ x, const int* __restrict__ counts,
    const int* __restrict__ poffs, const int* __restrict__ row_tok,
    unsigned short* __restrict__ xg)
{
    int t = threadIdx.x;
    int pr = blockIdx.x * 4 + t / 48;      // 4 rows / block, 48 threads / row
    int c0 = (t % 48) * 16;                // 16 elements / thread
    int e = 0;
#pragma unroll
    for (int i = 0; i < EE - 1; i++) if (pr >= poffs[i + 1]) e = i + 1;
    int local = pr - poffs[e];
    unsigned short* dst = xg + (size_t)pr * DD + c0;
    if (local < counts[e]) {
        int tok = row_tok[pr];
        const float4* sp = (const float4*)(x + (size_t)tok * DD + c0);
        alignas(16) unsigned short tmp[16];
#pragma unroll
        for (int j = 0; j < 4; j++) {
            float4 v = sp[j];
            tmp[4*j+0] = f2bf(v.x); tmp[4*j+1] = f2bf(v.y);
            tmp[4*j+2] = f2bf(v.z); tmp[4*j+3] = f2bf(v.w);
        }
        *(uint4*)dst       = *(uint4*)&tmp[0];
        *(uint4*)(dst + 8) = *(uint4*)&tmp[8];
    } else {
        uint4 z = {0, 0, 0, 0};
        *(uint4*)dst       = z;
        *(uint4*)(dst + 8) = z;
    }
}

// ---------------------------------------------------------------------------
// 4. Weight transpose + bf16 cast, latency-amortized: each block owns a
//    64-row x 256-col strip (4 tiles). ALL 16 global float4 loads issue
//    up front (one exposed HBM latency per block); loop is pure LDS+store.
// ---------------------------------------------------------------------------
__global__ __launch_bounds__(256) void transpose_cast_kernel(
    const float* __restrict__ W1, const float* __restrict__ W2,
    unsigned short* __restrict__ w1t, unsigned short* __restrict__ w2t)
{
    int z = blockIdx.z, e = blockIdx.y, bx = blockIdx.x;
    const float* src; unsigned short* dst; int R, C, SC;
    if (z == 0) { R = DD; C = HH; SC = 12; src = W1 + (size_t)e * R * C; dst = w1t + (size_t)e * R * C; }
    else        { R = HH; C = DD; SC = 3;  src = W2 + (size_t)e * R * C; dst = w2t + (size_t)e * R * C; }
    int rt = bx / SC, cs = bx % SC;
    int r0 = rt * 64, cbase = cs * 256;    // strip = 4 tiles of 64 cols

    __shared__ unsigned short tile[64][66];
    int tid = threadIdx.x;
    int lr = tid >> 2, lc = (tid & 3) * 16;     // load: row lr, 16 cols at lc
    int oc = tid >> 2, orr = (tid & 3) * 16;    // store: col oc, 16 rows at orr
    const float* srow = src + (size_t)(r0 + lr) * C + cbase + lc;

    float4 v[16];                        // 4 tiles x 64B/lane, all in flight
#pragma unroll
    for (int i = 0; i < 4; i++) {
        const float4* sp = (const float4*)(srow + i * 64);
#pragma unroll
        for (int j = 0; j < 4; j++) v[i * 4 + j] = sp[j];
    }

#pragma unroll
    for (int i = 0; i < 4; i++) {
        if (i) __syncthreads();           // prior col-reads done before overwrite
#pragma unroll
        for (int j = 0; j < 4; j++) {
            float4 t = v[i * 4 + j];
            tile[lr][lc + 4*j + 0] = f2bf(t.x);
            tile[lr][lc + 4*j + 1] = f2bf(t.y);
            tile[lr][lc + 4*j + 2] = f2bf(t.z);
            tile[lr][lc + 4*j + 3] = f2bf(t.w);
        }
        __syncthreads();
        alignas(16) unsigned short tmp[16];
#pragma unroll
        for (int j = 0; j < 16; j++) tmp[j] = tile[orr + j][oc];
        unsigned short* dp = dst + (size_t)(cbase + i * 64 + oc) * R + r0 + orr;
        *(uint4*)dp       = *(uint4*)&tmp[0];
        *(uint4*)(dp + 8) = *(uint4*)&tmp[8];
    }
}

// ---------------------------------------------------------------------------
// 5. GEMM1: h = gelu(xg @ W1[e]^T-layout) -> bf16.
//    Double-buffered: prefetch tile kt+1 via global_load_lds before computing
//    tile kt; single __syncthreads per K-step (T3-min 2-phase).
// ---------------------------------------------------------------------------
__global__ __launch_bounds__(256) void gemm1_kernel(
    const unsigned short* __restrict__ xg, const unsigned short* __restrict__ w1t,
    unsigned short* __restrict__ h, const int* __restrict__ poffs)
{
    int t = blockIdx.x;
    if (t * 128 >= poffs[EE]) return;
    int e = 0;
#pragma unroll
    for (int i = 0; i < EE - 1; i++) if (t * 128 >= poffs[i + 1]) e = i + 1;
    int row0 = t * 128, n0 = blockIdx.y * 128;

    __shared__ alignas(16) unsigned short As[2][128][32];
    __shared__ alignas(16) unsigned short Bs[2][128][32];

    int tid = threadIdx.x;
    int w = tid >> 6, lane = tid & 63;
    int quad = lane >> 4, l15 = lane & 15;
    int wm = (w & 1) * 64, wn = (w >> 1) * 64;

    const unsigned short* abase = xg + (size_t)row0 * DD;
    const unsigned short* bbase = w1t + (size_t)e * HH * DD + (size_t)n0 * DD;

    // chunk c covers shorts [c*8, c*8+8): row = c>>2, k-part = (c&3)*8
    int c0 = w * 64 + lane, c1 = 256 + c0;
    const unsigned short* ga0 = abase + (c0 >> 2) * DD + (c0 & 3) * 8;
    const unsigned short* ga1 = abase + (c1 >> 2) * DD + (c1 & 3) * 8;
    const unsigned short* gb0 = bbase + (c0 >> 2) * DD + (c0 & 3) * 8;
    const unsigned short* gb1 = bbase + (c1 >> 2) * DD + (c1 & 3) * 8;
    int lofs0 = (w * 64) * 8;            // wave-uniform short offsets
    int lofs1 = (256 + w * 64) * 8;

    floatx4 acc[4][4];
#pragma unroll
    for (int i = 0; i < 4; i++)
#pragma unroll
        for (int j = 0; j < 4; j++)
#pragma unroll
            for (int r = 0; r < 4; r++) acc[i][j][r] = 0.f;

    const int NT = DD / 32;
    // prologue: stage tile 0 into buffer 0
    gld16(ga0, &As[0][0][0] + lofs0);
    gld16(ga1, &As[0][0][0] + lofs1);
    gld16(gb0, &Bs[0][0][0] + lofs0);
    gld16(gb1, &Bs[0][0][0] + lofs1);
    __syncthreads();

    for (int kt = 0; kt < NT; kt++) {
        int cur = kt & 1;
        if (kt + 1 < NT) {                 // prefetch next tile into other buf
            int k0 = (kt + 1) * 32;
            unsigned short* nA = &As[cur ^ 1][0][0];
            unsigned short* nB = &Bs[cur ^ 1][0][0];
            gld16(ga0 + k0, nA + lofs0);
            gld16(ga1 + k0, nA + lofs1);
            gld16(gb0 + k0, nB + lofs0);
            gld16(gb1 + k0, nB + lofs1);
        }
        short8 afr[4], bfr[4];
#pragma unroll
        for (int fm = 0; fm < 4; fm++) afr[fm] = *(const short8*)&As[cur][wm + fm*16 + l15][quad * 8];
#pragma unroll
        for (int fn = 0; fn < 4; fn++) bfr[fn] = *(const short8*)&Bs[cur][wn + fn*16 + l15][quad * 8];
#pragma unroll
        for (int fm = 0; fm < 4; fm++)
#pragma unroll
            for (int fn = 0; fn < 4; fn++)
                acc[fm][fn] = __builtin_amdgcn_mfma_f32_16x16x32_bf16(afr[fm], bfr[fn], acc[fm][fn], 0, 0, 0);
        __syncthreads();   // drains prefetch (vmcnt 0) + LDS reads, joins waves
    }

#pragma unroll
    for (int fm = 0; fm < 4; fm++)
#pragma unroll
        for (int r = 0; r < 4; r++) {
            int rt = wm + fm * 16 + quad * 4 + r;
            size_t hrow = (size_t)(row0 + rt) * HH;
#pragma unroll
            for (int fn = 0; fn < 4; fn++) {
                int col = n0 + wn + fn * 16 + l15;
                float v = acc[fm][fn][r];
                float g = 0.5f * v * (1.f + erff(v * 0.70710678118654752f));
                h[hrow + col] = f2bf(g);
            }
        }
}

// ---------------------------------------------------------------------------
// 6. GEMM2: ybuf[kz][row] = h @ W2[e] partial (K split in 2). No atomics:
//    plain f32 stores into compact ybuf; combine_kernel reduces per token.
// ---------------------------------------------------------------------------
__global__ __launch_bounds__(256) void gemm2_kernel(
    const unsigned short* __restrict__ h, const unsigned short* __restrict__ w2t,
    float* __restrict__ ybuf, const int* __restrict__ poffs)
{
    int t = blockIdx.x;
    if (t * 128 >= poffs[EE]) return;
    int e = 0;
#pragma unroll
    for (int i = 0; i < EE - 1; i++) if (t * 128 >= poffs[i + 1]) e = i + 1;
    int row0 = t * 128, n0 = blockIdx.y * 128;
    int kz = blockIdx.z;                  // K-split: [kz*1536, kz*1536+1536)

    __shared__ alignas(16) unsigned short As[2][128][32];
    __shared__ alignas(16) unsigned short Bs[2][128][32];

    int tid = threadIdx.x;
    int w = tid >> 6, lane = tid & 63;
    int quad = lane >> 4, l15 = lane & 15;
    int wm = (w & 1) * 64, wn = (w >> 1) * 64;

    const unsigned short* abase = h + (size_t)row0 * HH + kz * (HH / 2);
    const unsigned short* bbase = w2t + (size_t)e * DD * HH + (size_t)n0 * HH + kz * (HH / 2);

    int c0 = w * 64 + lane, c1 = 256 + c0;
    const unsigned short* ga0 = abase + (c0 >> 2) * HH + (c0 & 3) * 8;
    const unsigned short* ga1 = abase + (c1 >> 2) * HH + (c1 & 3) * 8;
    const unsigned short* gb0 = bbase + (c0 >> 2) * HH + (c0 & 3) * 8;
    const unsigned short* gb1 = bbase + (c1 >> 2) * HH + (c1 & 3) * 8;
    int lofs0 = (w * 64) * 8;
    int lofs1 = (256 + w * 64) * 8;

    floatx4 acc[4][4];
#pragma unroll
    for (int i = 0; i < 4; i++)
#pragma unroll
        for (int j = 0; j < 4; j++)
#pragma unroll
            for (int r = 0; r < 4; r++) acc[i][j][r] = 0.f;

    const int NT = (HH / 2) / 32;
    gld16(ga0, &As[0][0][0] + lofs0);
    gld16(ga1, &As[0][0][0] + lofs1);
    gld16(gb0, &Bs[0][0][0] + lofs0);
    gld16(gb1, &Bs[0][0][0] + lofs1);
    __syncthreads();

    for (int kt = 0; kt < NT; kt++) {
        int cur = kt & 1;
        if (kt + 1 < NT) {
            int k0 = (kt + 1) * 32;
            unsigned short* nA = &As[cur ^ 1][0][0];
            unsigned short* nB = &Bs[cur ^ 1][0][0];
            gld16(ga0 + k0, nA + lofs0);
            gld16(ga1 + k0, nA + lofs1);
            gld16(gb0 + k0, nB + lofs0);
            gld16(gb1 + k0, nB + lofs1);
        }
        short8 afr[4], bfr[4];
#pragma unroll
        for (int fm = 0; fm < 4; fm++) afr[fm] = *(const short8*)&As[cur][wm + fm*16 + l15][quad * 8];
#pragma unroll
        for (int fn = 0; fn < 4; fn++) bfr[fn] = *(const short8*)&Bs[cur][wn + fn*16 + l15][quad * 8];
#pragma unroll
        for (int fm = 0; fm < 4; fm++)
#pragma unroll
            for (int fn = 0; fn < 4; fn++)
                acc[fm][fn] = __builtin_amdgcn_mfma_f32_16x16x32_bf16(afr[fm], bfr[fn], acc[fm][fn], 0, 0, 0);
        __syncthreads();
    }

    float* yb = ybuf + (size_t)kz * PP * DD + (size_t)row0 * DD;
#pragma unroll
    for (int fm = 0; fm < 4; fm++)
#pragma unroll
        for (int r = 0; r < 4; r++) {
            int rt = wm + fm * 16 + quad * 4 + r;
            float* op = yb + (size_t)rt * DD + n0 + wn;
#pragma unroll
            for (int fn = 0; fn < 4; fn++)
                op[fn * 16 + l15] = acc[fm][fn][r];
        }
}

// ---------------------------------------------------------------------------
// 7. Combine: out[n] = g0*(y[0][r0]+y[1][r0]) + g1*(y[0][r1]+y[1][r1])
// ---------------------------------------------------------------------------
__global__ __launch_bounds__(192) void combine_kernel(
    const float* __restrict__ ybuf, const int* __restrict__ inv_row,
    const float* __restrict__ top_g, float* __restrict__ out)
{
    int n = blockIdx.x;
    int c = threadIdx.x * 4;
    int r0 = inv_row[2*n], r1 = inv_row[2*n+1];
    float g0 = top_g[2*n], g1 = top_g[2*n+1];
    const size_t S = (size_t)PP * DD;
    const float* y0 = ybuf + (size_t)r0 * DD + c;
    const float* y1 = ybuf + (size_t)r1 * DD + c;
    float4 a0 = *(const float4*)y0, b0 = *(const float4*)(y0 + S);
    float4 a1 = *(const float4*)y1, b1 = *(const float4*)(y1 + S);
    float4 o;
    o.x = g0 * (a0.x + b0.x) + g1 * (a1.x + b1.x);
    o.y = g0 * (a0.y + b0.y) + g1 * (a1.y + b1.y);
    o.z = g0 * (a0.z + b0.z) + g1 * (a1.z + b1.z);
    o.w = g0 * (a0.w + b0.w) + g1 * (a1.w + b1.w);
    *(float4*)(out + (size_t)n * DD + c) = o;
}

// ---------------------------------------------------------------------------
extern "C" void kernel_launch(void* const* d_in, const int* in_sizes, int n_in,
                              void* d_out, int out_size, void* d_ws, size_t ws_size,
                              hipStream_t stream)
{
    const float* x  = (const float*)d_in[0];
    const float* Wr = (const float*)d_in[1];
    const float* W1 = (const float*)d_in[2];
    const float* W2 = (const float*)d_in[3];
    float* out = (float*)d_out;

    char* ws = (char*)d_ws;
    int*   counts   = (int*)(ws + 0);        // 8
    int*   cursor   = (int*)(ws + 32);       // 8
    float* psum     = (float*)(ws + 64);     // 8
    int*   poffs    = (int*)(ws + 96);       // 9
    int*   top_e    = (int*)(ws + 1024);                       // 4096 ints
    float* top_g    = (float*)(ws + 1024 + 16384);             // 4096 floats
    int*   row_tok  = (int*)(ws + 1024 + 2 * 16384);           // PP ints
    int*   inv_row  = (int*)(ws + 1024 + 2 * 16384 + PP * 4);  // 4096 ints
    size_t off = (size_t)(1024 + 2 * 16384 + PP * 4 + 16384 + 255) & ~(size_t)255;
    unsigned short* xg  = (unsigned short*)(ws + off); off += (size_t)PP * DD * 2;
    unsigned short* hbf = (unsigned short*)(ws + off); off += (size_t)PP * HH * 2;
    unsigned short* w1t = (unsigned short*)(ws + off); off += (size_t)EE * DD * HH * 2;
    unsigned short* w2t = (unsigned short*)(ws + off);
    // ybuf (2*PP*DD f32 = 31.5MB) aliases w1t (37.7MB): w1t is dead after
    // gemm1, rewritten by transpose_cast at the start of the next launch.
    float* ybuf = (float*)w1t;

    hipMemsetAsync(ws, 0, 96, stream);   // counts + cursor + psum

    transpose_cast_kernel<<<dim3(144, EE, 2), 256, 0, stream>>>(W1, W2, w1t, w2t);
    routing_kernel<<<dim3(NN / 16), 256, 0, stream>>>(x, Wr, counts, psum, top_e, top_g);
    scan_aux_kernel<<<1, 64, 0, stream>>>(counts, psum, cursor, poffs, out + (size_t)NN * DD);
    scatter_kernel<<<dim3(NN / 256), 256, 0, stream>>>(top_e, cursor, row_tok, inv_row);
    gather_cast_kernel<<<dim3(PP / 4), 192, 0, stream>>>(x, counts, poffs, row_tok, xg);
    gemm1_kernel<<<dim3(PT, HH / 128), 256, 0, stream>>>(xg, w1t, hbf, poffs);
    gemm2_kernel<<<dim3(PT, DD / 128, 2), 256, 0, stream>>>(hbf, w2t, ybuf, poffs);
    combine_kernel<<<dim3(NN), 192, 0, stream>>>(ybuf, inv_row, top_g, out);
}

// Round 6
// 346.958 us; speedup vs baseline: 1.3556x; 1.0007x over previous
//
#include <hip/hip_runtime.h>
#include <hip/hip_bf16.h>
#include <math.h>

#define DD 768
#define HH 3072
#define EE 8
#define NN 2048   // B*T tokens
#define PP 5120   // max padded compact rows (4096 + 8*128)
#define PT 40     // max padded m-tiles (PP/128)

typedef __attribute__((ext_vector_type(8))) short short8;   // 8 bf16 MFMA operand
typedef __attribute__((ext_vector_type(4))) float floatx4;  // MFMA accumulator

typedef const __attribute__((address_space(1))) void gas_void;
typedef __attribute__((address_space(3))) void las_void;

__device__ __forceinline__ void gld16(const void* g, void* l) {
    // async global->LDS DMA, 16B/lane; LDS dest = wave-uniform base + lane*16
    __builtin_amdgcn_global_load_lds((gas_void*)g, (las_void*)l, 16, 0, 0);
}

__device__ __forceinline__ unsigned short f2bf(float f) {
    union { float f; unsigned int u; } v; v.f = f;
    unsigned int u = v.u;
    u += 0x7fffu + ((u >> 16) & 1u);   // RNE (inputs finite)
    return (unsigned short)(u >> 16);
}

// ---------------------------------------------------------------------------
// 1. Routing: 16 lanes per token (D split 48 elems/lane), shfl reduce,
//    lane 0 does softmax/top-2. Grid 128 blocks -> all CUs engaged.
// ---------------------------------------------------------------------------
__global__ __launch_bounds__(256) void routing_kernel(
    const float* __restrict__ x, const float* __restrict__ Wr,
    int* __restrict__ counts, float* __restrict__ psum,
    int* __restrict__ top_e, float* __restrict__ top_g)
{
    __shared__ float wr[3 * DD];
    __shared__ float lpsum[EE];
    int tid = threadIdx.x;
    for (int i = tid; i < 3 * DD; i += 256) wr[i] = Wr[i];
    if (tid < EE) lpsum[tid] = 0.f;
    __syncthreads();

    int sub = tid & 15;                    // lane within 16-lane token group
    int n = blockIdx.x * 16 + (tid >> 4);  // 16 tokens per block
    const float* xr = x + (size_t)n * DD;
    float z0 = 0.f, z1 = 0.f, z2 = 0.f;
#pragma unroll
    for (int i = 0; i < DD / 64; i++) {
        int d = i * 64 + sub * 4;
        float4 v = *(const float4*)(xr + d);
        z0 = fmaf(v.x, wr[d], z0);         z0 = fmaf(v.y, wr[d+1], z0);
        z0 = fmaf(v.z, wr[d+2], z0);       z0 = fmaf(v.w, wr[d+3], z0);
        z1 = fmaf(v.x, wr[DD+d], z1);      z1 = fmaf(v.y, wr[DD+d+1], z1);
        z1 = fmaf(v.z, wr[DD+d+2], z1);    z1 = fmaf(v.w, wr[DD+d+3], z1);
        z2 = fmaf(v.x, wr[2*DD+d], z2);    z2 = fmaf(v.y, wr[2*DD+d+1], z2);
        z2 = fmaf(v.z, wr[2*DD+d+2], z2);  z2 = fmaf(v.w, wr[2*DD+d+3], z2);
    }
#pragma unroll
    for (int m = 8; m; m >>= 1) {
        z0 += __shfl_xor(z0, m, 16);
        z1 += __shfl_xor(z1, m, 16);
        z2 += __shfl_xor(z2, m, 16);
    }

    if (sub == 0) {
        const float r3 = 0.57735026918962576f; // 1/sqrt(3)
        float p[EE];
        float mx = -1e30f;
#pragma unroll
        for (int e = 0; e < EE; e++) {
            float s0 = (e & 4) ? z0 : -z0;   // itertools.product([-1,1]) order
            float s1 = (e & 2) ? z1 : -z1;
            float s2 = (e & 1) ? z2 : -z2;
            p[e] = (s0 + s1 + s2) * r3;
            mx = fmaxf(mx, p[e]);
        }
        float sum = 0.f;
#pragma unroll
        for (int e = 0; e < EE; e++) { p[e] = expf(p[e] - mx); sum += p[e]; }
        float inv_s = 1.f / sum;
#pragma unroll
        for (int e = 0; e < EE; e++) p[e] *= inv_s;

        int e1 = 0; float p1 = p[0];
#pragma unroll
        for (int e = 1; e < EE; e++) if (p[e] > p1) { p1 = p[e]; e1 = e; }
        int e2 = -1; float p2 = -1.f;
#pragma unroll
        for (int e = 0; e < EE; e++) if (e != e1 && p[e] > p2) { p2 = p[e]; e2 = e; }
        float inv_t = 1.f / (p1 + p2);
        top_e[2*n]   = e1;  top_g[2*n]   = p1 * inv_t;
        top_e[2*n+1] = e2;  top_g[2*n+1] = p2 * inv_t;
        atomicAdd(&counts[e1], 1);
        atomicAdd(&counts[e2], 1);
#pragma unroll
        for (int e = 0; e < EE; e++) atomicAdd(&lpsum[e], p[e]);
    }
    __syncthreads();
    if (tid < EE) atomicAdd(&psum[tid], lpsum[tid]);
}

// ---------------------------------------------------------------------------
// 2. Scan counts -> padded offsets (128-aligned), cursor, aux loss
// ---------------------------------------------------------------------------
__global__ void scan_aux_kernel(const int* __restrict__ counts, const float* __restrict__ psum,
                                int* __restrict__ cursor, int* __restrict__ poffs,
                                float* __restrict__ out_aux)
{
    if (threadIdx.x == 0) {
        int run = 0;
        for (int e = 0; e < EE; e++) {
            poffs[e] = run;
            cursor[e] = run;
            run += ((counts[e] + 127) >> 7) << 7;   // pad each expert to 128
        }
        poffs[EE] = run;
        float s = 0.f;
        for (int e = 0; e < EE; e++) {
            float t = psum[e] * (1.f / NN) - (1.f / EE);
            s += t * t;
        }
        *out_aux = 0.01f * (s * (1.f / EE));
    }
}

// ---------------------------------------------------------------------------
// 3. Scatter tokens into padded compact per-expert rows; record inverse map
// ---------------------------------------------------------------------------
__global__ __launch_bounds__(256) void scatter_kernel(
    const int* __restrict__ top_e, int* __restrict__ cursor,
    int* __restrict__ row_tok, int* __restrict__ inv_row)
{
    int n = blockIdx.x * 256 + threadIdx.x;
#pragma unroll
    for (int k = 0; k < 2; k++) {
        int e = top_e[2*n + k];
        int pos = atomicAdd(&cursor[e], 1);
        row_tok[pos]    = n;
        inv_row[2*n+k]  = pos;
    }
}

// ---------------------------------------------------------------------------
// 3b. Gather+cast: xg[pr] = bf16(x[row_tok[pr]]); zero pad rows
// ---------------------------------------------------------------------------
__global__ __launch_bounds__(192) void gather_cast_kernel(
    const float* __restrict__ x, const int* __restrict__ counts,
    const int* __restrict__ poffs, const int* __restrict__ row_tok,
    unsigned short* __restrict__ xg)
{
    int t = threadIdx.x;
    int pr = blockIdx.x * 4 + t / 48;      // 4 rows / block, 48 threads / row
    int c0 = (t % 48) * 16;                // 16 elements / thread
    int e = 0;
#pragma unroll
    for (int i = 0; i < EE - 1; i++) if (pr >= poffs[i + 1]) e = i + 1;
    int local = pr - poffs[e];
    unsigned short* dst = xg + (size_t)pr * DD + c0;
    if (local < counts[e]) {
        int tok = row_tok[pr];
        const float4* sp = (const float4*)(x + (size_t)tok * DD + c0);
        alignas(16) unsigned short tmp[16];
#pragma unroll
        for (int j = 0; j < 4; j++) {
            float4 v = sp[j];
            tmp[4*j+0] = f2bf(v.x); tmp[4*j+1] = f2bf(v.y);
            tmp[4*j+2] = f2bf(v.z); tmp[4*j+3] = f2bf(v.w);
        }
        *(uint4*)dst       = *(uint4*)&tmp[0];
        *(uint4*)(dst + 8) = *(uint4*)&tmp[8];
    } else {
        uint4 z = {0, 0, 0, 0};
        *(uint4*)dst       = z;
        *(uint4*)(dst + 8) = z;
    }
}

// ---------------------------------------------------------------------------
// 4. Weight transpose + bf16 cast, latency-amortized: each block owns a
//    64-row x 256-col strip (4 tiles). ALL 16 global float4 loads issue
//    up front; per-vector scalar asm pins (4 float "v" operands each —
//    float4 operands don't compile) keep all 16 loads live so the
//    compiler cannot sink them back into the loop (r4: VGPR=32 showed
//    the sink). One exposed HBM latency per block.
// ---------------------------------------------------------------------------
__global__ __launch_bounds__(256) void transpose_cast_kernel(
    const float* __restrict__ W1, const float* __restrict__ W2,
    unsigned short* __restrict__ w1t, unsigned short* __restrict__ w2t)
{
    int z = blockIdx.z, e = blockIdx.y, bx = blockIdx.x;
    const float* src; unsigned short* dst; int R, C, SC;
    if (z == 0) { R = DD; C = HH; SC = 12; src = W1 + (size_t)e * R * C; dst = w1t + (size_t)e * R * C; }
    else        { R = HH; C = DD; SC = 3;  src = W2 + (size_t)e * R * C; dst = w2t + (size_t)e * R * C; }
    int rt = bx / SC, cs = bx % SC;
    int r0 = rt * 64, cbase = cs * 256;    // strip = 4 tiles of 64 cols

    __shared__ unsigned short tile[64][66];
    int tid = threadIdx.x;
    int lr = tid >> 2, lc = (tid & 3) * 16;     // load: row lr, 16 cols at lc
    int oc = tid >> 2, orr = (tid & 3) * 16;    // store: col oc, 16 rows at orr
    const float* srow = src + (size_t)(r0 + lr) * C + cbase + lc;

    float4 v[16];                        // 4 tiles x 64B/lane, all in flight
#pragma unroll
    for (int i = 0; i < 4; i++) {
        const float4* sp = (const float4*)(srow + i * 64);
#pragma unroll
        for (int j = 0; j < 4; j++) v[i * 4 + j] = sp[j];
    }
    // Pin every component live here: forces back-to-back issue + single
    // wait; scalar float operands (vector operands are unsupported).
#pragma unroll
    for (int i = 0; i < 16; i++)
        asm volatile("" :: "v"(v[i].x), "v"(v[i].y), "v"(v[i].z), "v"(v[i].w));

#pragma unroll
    for (int i = 0; i < 4; i++) {
        if (i) __syncthreads();           // prior col-reads done before overwrite
#pragma unroll
        for (int j = 0; j < 4; j++) {
            float4 t = v[i * 4 + j];
            tile[lr][lc + 4*j + 0] = f2bf(t.x);
            tile[lr][lc + 4*j + 1] = f2bf(t.y);
            tile[lr][lc + 4*j + 2] = f2bf(t.z);
            tile[lr][lc + 4*j + 3] = f2bf(t.w);
        }
        __syncthreads();
        alignas(16) unsigned short tmp[16];
#pragma unroll
        for (int j = 0; j < 16; j++) tmp[j] = tile[orr + j][oc];
        unsigned short* dp = dst + (size_t)(cbase + i * 64 + oc) * R + r0 + orr;
        *(uint4*)dp       = *(uint4*)&tmp[0];
        *(uint4*)(dp + 8) = *(uint4*)&tmp[8];
    }
}

// ---------------------------------------------------------------------------
// 5. GEMM1: h = gelu(xg @ W1[e]^T-layout) -> bf16.
//    Double-buffered: prefetch tile kt+1 via global_load_lds before computing
//    tile kt; single __syncthreads per K-step (T3-min 2-phase).
// ---------------------------------------------------------------------------
__global__ __launch_bounds__(256) void gemm1_kernel(
    const unsigned short* __restrict__ xg, const unsigned short* __restrict__ w1t,
    unsigned short* __restrict__ h, const int* __restrict__ poffs)
{
    int t = blockIdx.x;
    if (t * 128 >= poffs[EE]) return;
    int e = 0;
#pragma unroll
    for (int i = 0; i < EE - 1; i++) if (t * 128 >= poffs[i + 1]) e = i + 1;
    int row0 = t * 128, n0 = blockIdx.y * 128;

    __shared__ alignas(16) unsigned short As[2][128][32];
    __shared__ alignas(16) unsigned short Bs[2][128][32];

    int tid = threadIdx.x;
    int w = tid >> 6, lane = tid & 63;
    int quad = lane >> 4, l15 = lane & 15;
    int wm = (w & 1) * 64, wn = (w >> 1) * 64;

    const unsigned short* abase = xg + (size_t)row0 * DD;
    const unsigned short* bbase = w1t + (size_t)e * HH * DD + (size_t)n0 * DD;

    // chunk c covers shorts [c*8, c*8+8): row = c>>2, k-part = (c&3)*8
    int c0 = w * 64 + lane, c1 = 256 + c0;
    const unsigned short* ga0 = abase + (c0 >> 2) * DD + (c0 & 3) * 8;
    const unsigned short* ga1 = abase + (c1 >> 2) * DD + (c1 & 3) * 8;
    const unsigned short* gb0 = bbase + (c0 >> 2) * DD + (c0 & 3) * 8;
    const unsigned short* gb1 = bbase + (c1 >> 2) * DD + (c1 & 3) * 8;
    int lofs0 = (w * 64) * 8;            // wave-uniform short offsets
    int lofs1 = (256 + w * 64) * 8;

    floatx4 acc[4][4];
#pragma unroll
    for (int i = 0; i < 4; i++)
#pragma unroll
        for (int j = 0; j < 4; j++)
#pragma unroll
            for (int r = 0; r < 4; r++) acc[i][j][r] = 0.f;

    const int NT = DD / 32;
    // prologue: stage tile 0 into buffer 0
    gld16(ga0, &As[0][0][0] + lofs0);
    gld16(ga1, &As[0][0][0] + lofs1);
    gld16(gb0, &Bs[0][0][0] + lofs0);
    gld16(gb1, &Bs[0][0][0] + lofs1);
    __syncthreads();

    for (int kt = 0; kt < NT; kt++) {
        int cur = kt & 1;
        if (kt + 1 < NT) {                 // prefetch next tile into other buf
            int k0 = (kt + 1) * 32;
            unsigned short* nA = &As[cur ^ 1][0][0];
            unsigned short* nB = &Bs[cur ^ 1][0][0];
            gld16(ga0 + k0, nA + lofs0);
            gld16(ga1 + k0, nA + lofs1);
            gld16(gb0 + k0, nB + lofs0);
            gld16(gb1 + k0, nB + lofs1);
        }
        short8 afr[4], bfr[4];
#pragma unroll
        for (int fm = 0; fm < 4; fm++) afr[fm] = *(const short8*)&As[cur][wm + fm*16 + l15][quad * 8];
#pragma unroll
        for (int fn = 0; fn < 4; fn++) bfr[fn] = *(const short8*)&Bs[cur][wn + fn*16 + l15][quad * 8];
#pragma unroll
        for (int fm = 0; fm < 4; fm++)
#pragma unroll
            for (int fn = 0; fn < 4; fn++)
                acc[fm][fn] = __builtin_amdgcn_mfma_f32_16x16x32_bf16(afr[fm], bfr[fn], acc[fm][fn], 0, 0, 0);
        __syncthreads();   // drains prefetch (vmcnt 0) + LDS reads, joins waves
    }

#pragma unroll
    for (int fm = 0; fm < 4; fm++)
#pragma unroll
        for (int r = 0; r < 4; r++) {
            int rt = wm + fm * 16 + quad * 4 + r;
            size_t hrow = (size_t)(row0 + rt) * HH;
#pragma unroll
            for (int fn = 0; fn < 4; fn++) {
                int col = n0 + wn + fn * 16 + l15;
                float v = acc[fm][fn][r];
                float g = 0.5f * v * (1.f + erff(v * 0.70710678118654752f));
                h[hrow + col] = f2bf(g);
            }
        }
}

// ---------------------------------------------------------------------------
// 6. GEMM2: ybuf[kz][row] = h @ W2[e] partial (K split in 2). No atomics:
//    plain f32 stores into compact ybuf; combine_kernel reduces per token.
// ---------------------------------------------------------------------------
__global__ __launch_bounds__(256) void gemm2_kernel(
    const unsigned short* __restrict__ h, const unsigned short* __restrict__ w2t,
    float* __restrict__ ybuf, const int* __restrict__ poffs)
{
    int t = blockIdx.x;
    if (t * 128 >= poffs[EE]) return;
    int e = 0;
#pragma unroll
    for (int i = 0; i < EE - 1; i++) if (t * 128 >= poffs[i + 1]) e = i + 1;
    int row0 = t * 128, n0 = blockIdx.y * 128;
    int kz = blockIdx.z;                  // K-split: [kz*1536, kz*1536+1536)

    __shared__ alignas(16) unsigned short As[2][128][32];
    __shared__ alignas(16) unsigned short Bs[2][128][32];

    int tid = threadIdx.x;
    int w = tid >> 6, lane = tid & 63;
    int quad = lane >> 4, l15 = lane & 15;
    int wm = (w & 1) * 64, wn = (w >> 1) * 64;

    const unsigned short* abase = h + (size_t)row0 * HH + kz * (HH / 2);
    const unsigned short* bbase = w2t + (size_t)e * DD * HH + (size_t)n0 * HH + kz * (HH / 2);

    int c0 = w * 64 + lane, c1 = 256 + c0;
    const unsigned short* ga0 = abase + (c0 >> 2) * HH + (c0 & 3) * 8;
    const unsigned short* ga1 = abase + (c1 >> 2) * HH + (c1 & 3) * 8;
    const unsigned short* gb0 = bbase + (c0 >> 2) * HH + (c0 & 3) * 8;
    const unsigned short* gb1 = bbase + (c1 >> 2) * HH + (c1 & 3) * 8;
    int lofs0 = (w * 64) * 8;
    int lofs1 = (256 + w * 64) * 8;

    floatx4 acc[4][4];
#pragma unroll
    for (int i = 0; i < 4; i++)
#pragma unroll
        for (int j = 0; j < 4; j++)
#pragma unroll
            for (int r = 0; r < 4; r++) acc[i][j][r] = 0.f;

    const int NT = (HH / 2) / 32;
    gld16(ga0, &As[0][0][0] + lofs0);
    gld16(ga1, &As[0][0][0] + lofs1);
    gld16(gb0, &Bs[0][0][0] + lofs0);
    gld16(gb1, &Bs[0][0][0] + lofs1);
    __syncthreads();

    for (int kt = 0; kt < NT; kt++) {
        int cur = kt & 1;
        if (kt + 1 < NT) {
            int k0 = (kt + 1) * 32;
            unsigned short* nA = &As[cur ^ 1][0][0];
            unsigned short* nB = &Bs[cur ^ 1][0][0];
            gld16(ga0 + k0, nA + lofs0);
            gld16(ga1 + k0, nA + lofs1);
            gld16(gb0 + k0, nB + lofs0);
            gld16(gb1 + k0, nB + lofs1);
        }
        short8 afr[4], bfr[4];
#pragma unroll
        for (int fm = 0; fm < 4; fm++) afr[fm] = *(const short8*)&As[cur][wm + fm*16 + l15][quad * 8];
#pragma unroll
        for (int fn = 0; fn < 4; fn++) bfr[fn] = *(const short8*)&Bs[cur][wn + fn*16 + l15][quad * 8];
#pragma unroll
        for (int fm = 0; fm < 4; fm++)
#pragma unroll
            for (int fn = 0; fn < 4; fn++)
                acc[fm][fn] = __builtin_amdgcn_mfma_f32_16x16x32_bf16(afr[fm], bfr[fn], acc[fm][fn], 0, 0, 0);
        __syncthreads();
    }

    float* yb = ybuf + (size_t)kz * PP * DD + (size_t)row0 * DD;
#pragma unroll
    for (int fm = 0; fm < 4; fm++)
#pragma unroll
        for (int r = 0; r < 4; r++) {
            int rt = wm + fm * 16 + quad * 4 + r;
            float* op = yb + (size_t)rt * DD + n0 + wn;
#pragma unroll
            for (int fn = 0; fn < 4; fn++)
                op[fn * 16 + l15] = acc[fm][fn][r];
        }
}

// ---------------------------------------------------------------------------
// 7. Combine: out[n] = g0*(y[0][r0]+y[1][r0]) + g1*(y[0][r1]+y[1][r1])
// ---------------------------------------------------------------------------
__global__ __launch_bounds__(192) void combine_kernel(
    const float* __restrict__ ybuf, const int* __restrict__ inv_row,
    const float* __restrict__ top_g, float* __restrict__ out)
{
    int n = blockIdx.x;
    int c = threadIdx.x * 4;
    int r0 = inv_row[2*n], r1 = inv_row[2*n+1];
    float g0 = top_g[2*n], g1 = top_g[2*n+1];
    const size_t S = (size_t)PP * DD;
    const float* y0 = ybuf + (size_t)r0 * DD + c;
    const float* y1 = ybuf + (size_t)r1 * DD + c;
    float4 a0 = *(const float4*)y0, b0 = *(const float4*)(y0 + S);
    float4 a1 = *(const float4*)y1, b1 = *(const float4*)(y1 + S);
    float4 o;
    o.x = g0 * (a0.x + b0.x) + g1 * (a1.x + b1.x);
    o.y = g0 * (a0.y + b0.y) + g1 * (a1.y + b1.y);
    o.z = g0 * (a0.z + b0.z) + g1 * (a1.z + b1.z);
    o.w = g0 * (a0.w + b0.w) + g1 * (a1.w + b1.w);
    *(float4*)(out + (size_t)n * DD + c) = o;
}

// ---------------------------------------------------------------------------
extern "C" void kernel_launch(void* const* d_in, const int* in_sizes, int n_in,
                              void* d_out, int out_size, void* d_ws, size_t ws_size,
                              hipStream_t stream)
{
    const float* x  = (const float*)d_in[0];
    const float* Wr = (const float*)d_in[1];
    const float* W1 = (const float*)d_in[2];
    const float* W2 = (const float*)d_in[3];
    float* out = (float*)d_out;

    char* ws = (char*)d_ws;
    int*   counts   = (int*)(ws + 0);        // 8
    int*   cursor   = (int*)(ws + 32);       // 8
    float* psum     = (float*)(ws + 64);     // 8
    int*   poffs    = (int*)(ws + 96);       // 9
    int*   top_e    = (int*)(ws + 1024);                       // 4096 ints
    float* top_g    = (float*)(ws + 1024 + 16384);             // 4096 floats
    int*   row_tok  = (int*)(ws + 1024 + 2 * 16384);           // PP ints
    int*   inv_row  = (int*)(ws + 1024 + 2 * 16384 + PP * 4);  // 4096 ints
    size_t off = (size_t)(1024 + 2 * 16384 + PP * 4 + 16384 + 255) & ~(size_t)255;
    unsigned short* xg  = (unsigned short*)(ws + off); off += (size_t)PP * DD * 2;
    unsigned short* hbf = (unsigned short*)(ws + off); off += (size_t)PP * HH * 2;
    unsigned short* w1t = (unsigned short*)(ws + off); off += (size_t)EE * DD * HH * 2;
    unsigned short* w2t = (unsigned short*)(ws + off);
    // ybuf (2*PP*DD f32 = 31.5MB) aliases w1t (37.7MB): w1t is dead after
    // gemm1, rewritten by transpose_cast at the start of the next launch.
    float* ybuf = (float*)w1t;

    hipMemsetAsync(ws, 0, 96, stream);   // counts + cursor + psum

    transpose_cast_kernel<<<dim3(144, EE, 2), 256, 0, stream>>>(W1, W2, w1t, w2t);
    routing_kernel<<<dim3(NN / 16), 256, 0, stream>>>(x, Wr, counts, psum, top_e, top_g);
    scan_aux_kernel<<<1, 64, 0, stream>>>(counts, psum, cursor, poffs, out + (size_t)NN * DD);
    scatter_kernel<<<dim3(NN / 256), 256, 0, stream>>>(top_e, cursor, row_tok, inv_row);
    gather_cast_kernel<<<dim3(PP / 4), 192, 0, stream>>>(x, counts, poffs, row_tok, xg);
    gemm1_kernel<<<dim3(PT, HH / 128), 256, 0, stream>>>(xg, w1t, hbf, poffs);
    gemm2_kernel<<<dim3(PT, DD / 128, 2), 256, 0, stream>>>(hbf, w2t, ybuf, poffs);
    combine_kernel<<<dim3(NN), 192, 0, stream>>>(ybuf, inv_row, top_g, out);
}

// Round 7
// 335.126 us; speedup vs baseline: 1.4035x; 1.0353x over previous
//
#include <hip/hip_runtime.h>
#include <hip/hip_bf16.h>
#include <math.h>

#define DD 768
#define HH 3072
#define EE 8
#define NN 2048   // B*T tokens
#define PP 5120   // max padded compact rows (4096 + 8*128)
#define PT 40     // max padded m-tiles (PP/128)

typedef __attribute__((ext_vector_type(8))) short short8;   // 8 bf16 MFMA operand
typedef __attribute__((ext_vector_type(4))) float floatx4;  // MFMA accumulator

typedef const __attribute__((address_space(1))) void gas_void;
typedef __attribute__((address_space(3))) void las_void;

__device__ __forceinline__ void gld16(const void* g, void* l) {
    // async global->LDS DMA, 16B/lane; LDS dest = wave-uniform base + lane*16
    __builtin_amdgcn_global_load_lds((gas_void*)g, (las_void*)l, 16, 0, 0);
}

__device__ __forceinline__ unsigned short f2bf(float f) {
    union { float f; unsigned int u; } v; v.f = f;
    unsigned int u = v.u;
    u += 0x7fffu + ((u >> 16) & 1u);   // RNE (inputs finite)
    return (unsigned short)(u >> 16);
}

// ---------------------------------------------------------------------------
// 1. Routing: 16 lanes per token (D split 48 elems/lane), shfl reduce,
//    lane 0 does softmax/top-2. Grid 128 blocks -> all CUs engaged.
// ---------------------------------------------------------------------------
__global__ __launch_bounds__(256) void routing_kernel(
    const float* __restrict__ x, const float* __restrict__ Wr,
    int* __restrict__ counts, float* __restrict__ psum,
    int* __restrict__ top_e, float* __restrict__ top_g)
{
    __shared__ float wr[3 * DD];
    __shared__ float lpsum[EE];
    int tid = threadIdx.x;
    for (int i = tid; i < 3 * DD; i += 256) wr[i] = Wr[i];
    if (tid < EE) lpsum[tid] = 0.f;
    __syncthreads();

    int sub = tid & 15;                    // lane within 16-lane token group
    int n = blockIdx.x * 16 + (tid >> 4);  // 16 tokens per block
    const float* xr = x + (size_t)n * DD;
    float z0 = 0.f, z1 = 0.f, z2 = 0.f;
#pragma unroll
    for (int i = 0; i < DD / 64; i++) {
        int d = i * 64 + sub * 4;
        float4 v = *(const float4*)(xr + d);
        z0 = fmaf(v.x, wr[d], z0);         z0 = fmaf(v.y, wr[d+1], z0);
        z0 = fmaf(v.z, wr[d+2], z0);       z0 = fmaf(v.w, wr[d+3], z0);
        z1 = fmaf(v.x, wr[DD+d], z1);      z1 = fmaf(v.y, wr[DD+d+1], z1);
        z1 = fmaf(v.z, wr[DD+d+2], z1);    z1 = fmaf(v.w, wr[DD+d+3], z1);
        z2 = fmaf(v.x, wr[2*DD+d], z2);    z2 = fmaf(v.y, wr[2*DD+d+1], z2);
        z2 = fmaf(v.z, wr[2*DD+d+2], z2);  z2 = fmaf(v.w, wr[2*DD+d+3], z2);
    }
#pragma unroll
    for (int m = 8; m; m >>= 1) {
        z0 += __shfl_xor(z0, m, 16);
        z1 += __shfl_xor(z1, m, 16);
        z2 += __shfl_xor(z2, m, 16);
    }

    if (sub == 0) {
        const float r3 = 0.57735026918962576f; // 1/sqrt(3)
        float p[EE];
        float mx = -1e30f;
#pragma unroll
        for (int e = 0; e < EE; e++) {
            float s0 = (e & 4) ? z0 : -z0;   // itertools.product([-1,1]) order
            float s1 = (e & 2) ? z1 : -z1;
            float s2 = (e & 1) ? z2 : -z2;
            p[e] = (s0 + s1 + s2) * r3;
            mx = fmaxf(mx, p[e]);
        }
        float sum = 0.f;
#pragma unroll
        for (int e = 0; e < EE; e++) { p[e] = expf(p[e] - mx); sum += p[e]; }
        float inv_s = 1.f / sum;
#pragma unroll
        for (int e = 0; e < EE; e++) p[e] *= inv_s;

        int e1 = 0; float p1 = p[0];
#pragma unroll
        for (int e = 1; e < EE; e++) if (p[e] > p1) { p1 = p[e]; e1 = e; }
        int e2 = -1; float p2 = -1.f;
#pragma unroll
        for (int e = 0; e < EE; e++) if (e != e1 && p[e] > p2) { p2 = p[e]; e2 = e; }
        float inv_t = 1.f / (p1 + p2);
        top_e[2*n]   = e1;  top_g[2*n]   = p1 * inv_t;
        top_e[2*n+1] = e2;  top_g[2*n+1] = p2 * inv_t;
        atomicAdd(&counts[e1], 1);
        atomicAdd(&counts[e2], 1);
#pragma unroll
        for (int e = 0; e < EE; e++) atomicAdd(&lpsum[e], p[e]);
    }
    __syncthreads();
    if (tid < EE) atomicAdd(&psum[tid], lpsum[tid]);
}

// ---------------------------------------------------------------------------
// 2. Scan counts -> padded offsets (128-aligned), cursor, aux loss
// ---------------------------------------------------------------------------
__global__ void scan_aux_kernel(const int* __restrict__ counts, const float* __restrict__ psum,
                                int* __restrict__ cursor, int* __restrict__ poffs,
                                float* __restrict__ out_aux)
{
    if (threadIdx.x == 0) {
        int run = 0;
        for (int e = 0; e < EE; e++) {
            poffs[e] = run;
            cursor[e] = run;
            run += ((counts[e] + 127) >> 7) << 7;   // pad each expert to 128
        }
        poffs[EE] = run;
        float s = 0.f;
        for (int e = 0; e < EE; e++) {
            float t = psum[e] * (1.f / NN) - (1.f / EE);
            s += t * t;
        }
        *out_aux = 0.01f * (s * (1.f / EE));
    }
}

// ---------------------------------------------------------------------------
// 3. Scatter tokens into padded compact per-expert rows; record inverse map
// ---------------------------------------------------------------------------
__global__ __launch_bounds__(256) void scatter_kernel(
    const int* __restrict__ top_e, int* __restrict__ cursor,
    int* __restrict__ row_tok, int* __restrict__ inv_row)
{
    int n = blockIdx.x * 256 + threadIdx.x;
#pragma unroll
    for (int k = 0; k < 2; k++) {
        int e = top_e[2*n + k];
        int pos = atomicAdd(&cursor[e], 1);
        row_tok[pos]    = n;
        inv_row[2*n+k]  = pos;
    }
}

// ---------------------------------------------------------------------------
// 3b. Gather+cast: xg[pr] = bf16(x[row_tok[pr]]); zero pad rows
// ---------------------------------------------------------------------------
__global__ __launch_bounds__(192) void gather_cast_kernel(
    const float* __restrict__ x, const int* __restrict__ counts,
    const int* __restrict__ poffs, const int* __restrict__ row_tok,
    unsigned short* __restrict__ xg)
{
    int t = threadIdx.x;
    int pr = blockIdx.x * 4 + t / 48;      // 4 rows / block, 48 threads / row
    int c0 = (t % 48) * 16;                // 16 elements / thread
    int e = 0;
#pragma unroll
    for (int i = 0; i < EE - 1; i++) if (pr >= poffs[i + 1]) e = i + 1;
    int local = pr - poffs[e];
    unsigned short* dst = xg + (size_t)pr * DD + c0;
    if (local < counts[e]) {
        int tok = row_tok[pr];
        const float4* sp = (const float4*)(x + (size_t)tok * DD + c0);
        alignas(16) unsigned short tmp[16];
#pragma unroll
        for (int j = 0; j < 4; j++) {
            float4 v = sp[j];
            tmp[4*j+0] = f2bf(v.x); tmp[4*j+1] = f2bf(v.y);
            tmp[4*j+2] = f2bf(v.z); tmp[4*j+3] = f2bf(v.w);
        }
        *(uint4*)dst       = *(uint4*)&tmp[0];
        *(uint4*)(dst + 8) = *(uint4*)&tmp[8];
    } else {
        uint4 z = {0, 0, 0, 0};
        *(uint4*)dst       = z;
        *(uint4*)(dst + 8) = z;
    }
}

// ---------------------------------------------------------------------------
// 4. Weight transpose + bf16 cast (64x256 strip, front-loaded loads + pin)
// ---------------------------------------------------------------------------
__global__ __launch_bounds__(256) void transpose_cast_kernel(
    const float* __restrict__ W1, const float* __restrict__ W2,
    unsigned short* __restrict__ w1t, unsigned short* __restrict__ w2t)
{
    int z = blockIdx.z, e = blockIdx.y, bx = blockIdx.x;
    const float* src; unsigned short* dst; int R, C, SC;
    if (z == 0) { R = DD; C = HH; SC = 12; src = W1 + (size_t)e * R * C; dst = w1t + (size_t)e * R * C; }
    else        { R = HH; C = DD; SC = 3;  src = W2 + (size_t)e * R * C; dst = w2t + (size_t)e * R * C; }
    int rt = bx / SC, cs = bx % SC;
    int r0 = rt * 64, cbase = cs * 256;    // strip = 4 tiles of 64 cols

    __shared__ unsigned short tile[64][66];
    int tid = threadIdx.x;
    int lr = tid >> 2, lc = (tid & 3) * 16;     // load: row lr, 16 cols at lc
    int oc = tid >> 2, orr = (tid & 3) * 16;    // store: col oc, 16 rows at orr
    const float* srow = src + (size_t)(r0 + lr) * C + cbase + lc;

    float4 v[16];                        // 4 tiles x 64B/lane, all in flight
#pragma unroll
    for (int i = 0; i < 4; i++) {
        const float4* sp = (const float4*)(srow + i * 64);
#pragma unroll
        for (int j = 0; j < 4; j++) v[i * 4 + j] = sp[j];
    }
    // Pin every component live here: forces back-to-back issue + single
    // wait; scalar float operands (vector operands are unsupported).
#pragma unroll
    for (int i = 0; i < 16; i++)
        asm volatile("" :: "v"(v[i].x), "v"(v[i].y), "v"(v[i].z), "v"(v[i].w));

#pragma unroll
    for (int i = 0; i < 4; i++) {
        if (i) __syncthreads();           // prior col-reads done before overwrite
#pragma unroll
        for (int j = 0; j < 4; j++) {
            float4 t = v[i * 4 + j];
            tile[lr][lc + 4*j + 0] = f2bf(t.x);
            tile[lr][lc + 4*j + 1] = f2bf(t.y);
            tile[lr][lc + 4*j + 2] = f2bf(t.z);
            tile[lr][lc + 4*j + 3] = f2bf(t.w);
        }
        __syncthreads();
        alignas(16) unsigned short tmp[16];
#pragma unroll
        for (int j = 0; j < 16; j++) tmp[j] = tile[orr + j][oc];
        unsigned short* dp = dst + (size_t)(cbase + i * 64 + oc) * R + r0 + orr;
        *(uint4*)dp       = *(uint4*)&tmp[0];
        *(uint4*)(dp + 8) = *(uint4*)&tmp[8];
    }
}

// ---------------------------------------------------------------------------
// 5. GEMM1: h = gelu(xg @ W1[e]^T-layout) -> bf16.
//    T4 counted-vmcnt pipeline, 3 LDS buffers, prefetch 2 K-steps ahead:
//    raw s_barrier + s_waitcnt vmcnt(4) keeps the kt+2 stage in flight
//    across the barrier (r6: vmcnt(0)-drain exposed ~600cyc/iter).
// ---------------------------------------------------------------------------
__global__ __launch_bounds__(256) void gemm1_kernel(
    const unsigned short* __restrict__ xg, const unsigned short* __restrict__ w1t,
    unsigned short* __restrict__ h, const int* __restrict__ poffs)
{
    int t = blockIdx.x;
    if (t * 128 >= poffs[EE]) return;
    int e = 0;
#pragma unroll
    for (int i = 0; i < EE - 1; i++) if (t * 128 >= poffs[i + 1]) e = i + 1;
    int row0 = t * 128, n0 = blockIdx.y * 128;

    __shared__ alignas(16) unsigned short As[3][128][32];   // 3 x 8KB
    __shared__ alignas(16) unsigned short Bs[3][128][32];

    int tid = threadIdx.x;
    int w = tid >> 6, lane = tid & 63;
    int quad = lane >> 4, l15 = lane & 15;
    int wm = (w & 1) * 64, wn = (w >> 1) * 64;

    const unsigned short* abase = xg + (size_t)row0 * DD;
    const unsigned short* bbase = w1t + (size_t)e * HH * DD + (size_t)n0 * DD;

    // chunk c covers shorts [c*8, c*8+8): row = c>>2, k-part = (c&3)*8
    int c0 = w * 64 + lane, c1 = 256 + c0;
    const unsigned short* ga0 = abase + (c0 >> 2) * DD + (c0 & 3) * 8;
    const unsigned short* ga1 = abase + (c1 >> 2) * DD + (c1 & 3) * 8;
    const unsigned short* gb0 = bbase + (c0 >> 2) * DD + (c0 & 3) * 8;
    const unsigned short* gb1 = bbase + (c1 >> 2) * DD + (c1 & 3) * 8;
    int lofs0 = (w * 64) * 8;            // wave-uniform short offsets
    int lofs1 = (256 + w * 64) * 8;
    unsigned short* asb = &As[0][0][0];
    unsigned short* bsb = &Bs[0][0][0];

    floatx4 acc[4][4];
#pragma unroll
    for (int i = 0; i < 4; i++)
#pragma unroll
        for (int j = 0; j < 4; j++)
#pragma unroll
            for (int r = 0; r < 4; r++) acc[i][j][r] = 0.f;

    const int NT = DD / 32;   // 24
    // prologue: stage 0 -> buf0, stage 1 -> buf1; wait stage0 only
    gld16(ga0,      asb + lofs0);  gld16(ga1,      asb + lofs1);
    gld16(gb0,      bsb + lofs0);  gld16(gb1,      bsb + lofs1);
    gld16(ga0 + 32, asb + 4096 + lofs0);  gld16(ga1 + 32, asb + 4096 + lofs1);
    gld16(gb0 + 32, bsb + 4096 + lofs0);  gld16(gb1 + 32, bsb + 4096 + lofs1);
    asm volatile("s_waitcnt vmcnt(4)" ::: "memory");
    asm volatile("s_barrier" ::: "memory");

    int cur = 0, pre = 2;   // pre = buffer receiving stage kt+2
    for (int kt = 0; kt < NT; kt++) {
        const unsigned short* A = asb + cur * 4096;
        const unsigned short* B = bsb + cur * 4096;
        short8 afr[4], bfr[4];
#pragma unroll
        for (int fm = 0; fm < 4; fm++) afr[fm] = *(const short8*)(A + (wm + fm*16 + l15) * 32 + quad * 8);
#pragma unroll
        for (int fn = 0; fn < 4; fn++) bfr[fn] = *(const short8*)(B + (wn + fn*16 + l15) * 32 + quad * 8);
        if (kt < NT - 2) {               // issue stage kt+2 early
            int k0 = (kt + 2) * 32;
            unsigned short* PA = asb + pre * 4096;
            unsigned short* PB = bsb + pre * 4096;
            gld16(ga0 + k0, PA + lofs0);  gld16(ga1 + k0, PA + lofs1);
            gld16(gb0 + k0, PB + lofs0);  gld16(gb1 + k0, PB + lofs1);
        }
#pragma unroll
        for (int fm = 0; fm < 4; fm++)
#pragma unroll
            for (int fn = 0; fn < 4; fn++)
                acc[fm][fn] = __builtin_amdgcn_mfma_f32_16x16x32_bf16(afr[fm], bfr[fn], acc[fm][fn], 0, 0, 0);
        if (kt < NT - 2) asm volatile("s_waitcnt vmcnt(4) lgkmcnt(0)" ::: "memory");
        else             asm volatile("s_waitcnt vmcnt(0) lgkmcnt(0)" ::: "memory");
        asm volatile("s_barrier" ::: "memory");
        cur = (cur == 2) ? 0 : cur + 1;
        pre = (pre == 2) ? 0 : pre + 1;
    }

#pragma unroll
    for (int fm = 0; fm < 4; fm++)
#pragma unroll
        for (int r = 0; r < 4; r++) {
            int rt = wm + fm * 16 + quad * 4 + r;
            size_t hrow = (size_t)(row0 + rt) * HH;
#pragma unroll
            for (int fn = 0; fn < 4; fn++) {
                int col = n0 + wn + fn * 16 + l15;
                float v = acc[fm][fn][r];
                float g = 0.5f * v * (1.f + erff(v * 0.70710678118654752f));
                h[hrow + col] = f2bf(g);
            }
        }
}

// ---------------------------------------------------------------------------
// 6. GEMM2: ybuf[kz][row] = h @ W2[e] partial (K split in 2). Same T4
//    counted-vmcnt 3-buffer pipeline. Plain f32 stores; combine reduces.
// ---------------------------------------------------------------------------
__global__ __launch_bounds__(256) void gemm2_kernel(
    const unsigned short* __restrict__ h, const unsigned short* __restrict__ w2t,
    float* __restrict__ ybuf, const int* __restrict__ poffs)
{
    int t = blockIdx.x;
    if (t * 128 >= poffs[EE]) return;
    int e = 0;
#pragma unroll
    for (int i = 0; i < EE - 1; i++) if (t * 128 >= poffs[i + 1]) e = i + 1;
    int row0 = t * 128, n0 = blockIdx.y * 128;
    int kz = blockIdx.z;                  // K-split: [kz*1536, kz*1536+1536)

    __shared__ alignas(16) unsigned short As[3][128][32];
    __shared__ alignas(16) unsigned short Bs[3][128][32];

    int tid = threadIdx.x;
    int w = tid >> 6, lane = tid & 63;
    int quad = lane >> 4, l15 = lane & 15;
    int wm = (w & 1) * 64, wn = (w >> 1) * 64;

    const unsigned short* abase = h + (size_t)row0 * HH + kz * (HH / 2);
    const unsigned short* bbase = w2t + (size_t)e * DD * HH + (size_t)n0 * HH + kz * (HH / 2);

    int c0 = w * 64 + lane, c1 = 256 + c0;
    const unsigned short* ga0 = abase + (c0 >> 2) * HH + (c0 & 3) * 8;
    const unsigned short* ga1 = abase + (c1 >> 2) * HH + (c1 & 3) * 8;
    const unsigned short* gb0 = bbase + (c0 >> 2) * HH + (c0 & 3) * 8;
    const unsigned short* gb1 = bbase + (c1 >> 2) * HH + (c1 & 3) * 8;
    int lofs0 = (w * 64) * 8;
    int lofs1 = (256 + w * 64) * 8;
    unsigned short* asb = &As[0][0][0];
    unsigned short* bsb = &Bs[0][0][0];

    floatx4 acc[4][4];
#pragma unroll
    for (int i = 0; i < 4; i++)
#pragma unroll
        for (int j = 0; j < 4; j++)
#pragma unroll
            for (int r = 0; r < 4; r++) acc[i][j][r] = 0.f;

    const int NT = (HH / 2) / 32;   // 48
    gld16(ga0,      asb + lofs0);  gld16(ga1,      asb + lofs1);
    gld16(gb0,      bsb + lofs0);  gld16(gb1,      bsb + lofs1);
    gld16(ga0 + 32, asb + 4096 + lofs0);  gld16(ga1 + 32, asb + 4096 + lofs1);
    gld16(gb0 + 32, bsb + 4096 + lofs0);  gld16(gb1 + 32, bsb + 4096 + lofs1);
    asm volatile("s_waitcnt vmcnt(4)" ::: "memory");
    asm volatile("s_barrier" ::: "memory");

    int cur = 0, pre = 2;
    for (int kt = 0; kt < NT; kt++) {
        const unsigned short* A = asb + cur * 4096;
        const unsigned short* B = bsb + cur * 4096;
        short8 afr[4], bfr[4];
#pragma unroll
        for (int fm = 0; fm < 4; fm++) afr[fm] = *(const short8*)(A + (wm + fm*16 + l15) * 32 + quad * 8);
#pragma unroll
        for (int fn = 0; fn < 4; fn++) bfr[fn] = *(const short8*)(B + (wn + fn*16 + l15) * 32 + quad * 8);
        if (kt < NT - 2) {
            int k0 = (kt + 2) * 32;
            unsigned short* PA = asb + pre * 4096;
            unsigned short* PB = bsb + pre * 4096;
            gld16(ga0 + k0, PA + lofs0);  gld16(ga1 + k0, PA + lofs1);
            gld16(gb0 + k0, PB + lofs0);  gld16(gb1 + k0, PB + lofs1);
        }
#pragma unroll
        for (int fm = 0; fm < 4; fm++)
#pragma unroll
            for (int fn = 0; fn < 4; fn++)
                acc[fm][fn] = __builtin_amdgcn_mfma_f32_16x16x32_bf16(afr[fm], bfr[fn], acc[fm][fn], 0, 0, 0);
        if (kt < NT - 2) asm volatile("s_waitcnt vmcnt(4) lgkmcnt(0)" ::: "memory");
        else             asm volatile("s_waitcnt vmcnt(0) lgkmcnt(0)" ::: "memory");
        asm volatile("s_barrier" ::: "memory");
        cur = (cur == 2) ? 0 : cur + 1;
        pre = (pre == 2) ? 0 : pre + 1;
    }

    float* yb = ybuf + (size_t)kz * PP * DD + (size_t)row0 * DD;
#pragma unroll
    for (int fm = 0; fm < 4; fm++)
#pragma unroll
        for (int r = 0; r < 4; r++) {
            int rt = wm + fm * 16 + quad * 4 + r;
            float* op = yb + (size_t)rt * DD + n0 + wn;
#pragma unroll
            for (int fn = 0; fn < 4; fn++)
                op[fn * 16 + l15] = acc[fm][fn][r];
        }
}

// ---------------------------------------------------------------------------
// 7. Combine: out[n] = g0*(y[0][r0]+y[1][r0]) + g1*(y[0][r1]+y[1][r1])
// ---------------------------------------------------------------------------
__global__ __launch_bounds__(192) void combine_kernel(
    const float* __restrict__ ybuf, const int* __restrict__ inv_row,
    const float* __restrict__ top_g, float* __restrict__ out)
{
    int n = blockIdx.x;
    int c = threadIdx.x * 4;
    int r0 = inv_row[2*n], r1 = inv_row[2*n+1];
    float g0 = top_g[2*n], g1 = top_g[2*n+1];
    const size_t S = (size_t)PP * DD;
    const float* y0 = ybuf + (size_t)r0 * DD + c;
    const float* y1 = ybuf + (size_t)r1 * DD + c;
    float4 a0 = *(const float4*)y0, b0 = *(const float4*)(y0 + S);
    float4 a1 = *(const float4*)y1, b1 = *(const float4*)(y1 + S);
    float4 o;
    o.x = g0 * (a0.x + b0.x) + g1 * (a1.x + b1.x);
    o.y = g0 * (a0.y + b0.y) + g1 * (a1.y + b1.y);
    o.z = g0 * (a0.z + b0.z) + g1 * (a1.z + b1.z);
    o.w = g0 * (a0.w + b0.w) + g1 * (a1.w + b1.w);
    *(float4*)(out + (size_t)n * DD + c) = o;
}

// ---------------------------------------------------------------------------
extern "C" void kernel_launch(void* const* d_in, const int* in_sizes, int n_in,
                              void* d_out, int out_size, void* d_ws, size_t ws_size,
                              hipStream_t stream)
{
    const float* x  = (const float*)d_in[0];
    const float* Wr = (const float*)d_in[1];
    const float* W1 = (const float*)d_in[2];
    const float* W2 = (const float*)d_in[3];
    float* out = (float*)d_out;

    char* ws = (char*)d_ws;
    int*   counts   = (int*)(ws + 0);        // 8
    int*   cursor   = (int*)(ws + 32);       // 8
    float* psum     = (float*)(ws + 64);     // 8
    int*   poffs    = (int*)(ws + 96);       // 9
    int*   top_e    = (int*)(ws + 1024);                       // 4096 ints
    float* top_g    = (float*)(ws + 1024 + 16384);             // 4096 floats
    int*   row_tok  = (int*)(ws + 1024 + 2 * 16384);           // PP ints
    int*   inv_row  = (int*)(ws + 1024 + 2 * 16384 + PP * 4);  // 4096 ints
    size_t off = (size_t)(1024 + 2 * 16384 + PP * 4 + 16384 + 255) & ~(size_t)255;
    unsigned short* xg  = (unsigned short*)(ws + off); off += (size_t)PP * DD * 2;
    unsigned short* hbf = (unsigned short*)(ws + off); off += (size_t)PP * HH * 2;
    unsigned short* w1t = (unsigned short*)(ws + off); off += (size_t)EE * DD * HH * 2;
    unsigned short* w2t = (unsigned short*)(ws + off);
    // ybuf (2*PP*DD f32 = 31.5MB) aliases w1t (37.7MB): w1t is dead after
    // gemm1, rewritten by transpose_cast at the start of the next launch.
    float* ybuf = (float*)w1t;

    hipMemsetAsync(ws, 0, 96, stream);   // counts + cursor + psum

    transpose_cast_kernel<<<dim3(144, EE, 2), 256, 0, stream>>>(W1, W2, w1t, w2t);
    routing_kernel<<<dim3(NN / 16), 256, 0, stream>>>(x, Wr, counts, psum, top_e, top_g);
    scan_aux_kernel<<<1, 64, 0, stream>>>(counts, psum, cursor, poffs, out + (size_t)NN * DD);
    scatter_kernel<<<dim3(NN / 256), 256, 0, stream>>>(top_e, cursor, row_tok, inv_row);
    gather_cast_kernel<<<dim3(PP / 4), 192, 0, stream>>>(x, counts, poffs, row_tok, xg);
    gemm1_kernel<<<dim3(PT, HH / 128), 256, 0, stream>>>(xg, w1t, hbf, poffs);
    gemm2_kernel<<<dim3(PT, DD / 128, 2), 256, 0, stream>>>(hbf, w2t, ybuf, poffs);
    combine_kernel<<<dim3(NN), 192, 0, stream>>>(ybuf, inv_row, top_g, out);
}